// Round 2
// baseline (3158.695 us; speedup 1.0000x reference)
//
#include <hip/hip_runtime.h>
#include <math.h>

#define NN   100000
#define EE   800000
#define RR   6
#define BB   1000
#define HH   128
#define MM   (RR*NN)
#define NBPR ((NN + 255) >> 8)       // 391 buckets per relation (256 dst each)
#define NBK  (RR * NBPR)             // 2346

static inline int ceil_div(int a, int b){ return (a+b-1)/b; }

typedef __attribute__((ext_vector_type(8))) short bf16x8;
typedef __attribute__((ext_vector_type(4))) short bf16x4;
typedef __attribute__((ext_vector_type(4))) float f32x4;

__device__ __forceinline__ unsigned fenc(float f){
  unsigned u = __float_as_uint(f);
  return (u & 0x80000000u) ? ~u : (u | 0x80000000u);
}
__device__ __forceinline__ float fdec(unsigned u){
  return __uint_as_float((u & 0x80000000u) ? (u & 0x7fffffffu) : ~u);
}
__device__ __forceinline__ unsigned short f2bf(float f){
  unsigned u = __float_as_uint(f);
  return (unsigned short)((u + 0x7fffu + ((u >> 16) & 1u)) >> 16);
}
__device__ __forceinline__ float bf2f(unsigned short h){
  return __uint_as_float(((unsigned)h) << 16);
}

// ================= bucketed CSR build =================
__global__ void k_bcount(const int* __restrict__ edges, int* __restrict__ bcnt)
{
  int gid = blockIdx.x*256 + threadIdx.x;
  if (gid >= RR*EE) return;
  int r = gid / EE, e = gid - r*EE;
  int dst = edges[(size_t)r*2*EE + EE + e];
  atomicAdd(&bcnt[r*NBPR + (dst >> 8)], 1);
}

__global__ void k_bscan(const int* __restrict__ bcnt, int* __restrict__ boff,
                        int* __restrict__ off)
{
  __shared__ int sh[256];
  int t = threadIdx.x;
  int carry = 0;
  for (int c = 0; c < NBK; c += 256) {
    int idx = c + t;
    int v = (idx < NBK) ? bcnt[idx] : 0;
    sh[t] = v;
    __syncthreads();
    for (int o = 1; o < 256; o <<= 1) {
      int add = (t >= o) ? sh[t-o] : 0;
      __syncthreads();
      sh[t] += add;
      __syncthreads();
    }
    int incl = sh[t];
    int tot  = sh[255];
    if (idx < NBK) boff[idx] = carry + incl - v;
    __syncthreads();
    carry += tot;
  }
  if (t == 0) { boff[NBK] = carry; off[MM] = carry; }
}

__global__ void k_bscatter(const int* __restrict__ edges, const int* __restrict__ boff,
                           int* __restrict__ bcur, unsigned* __restrict__ ebkt)
{
  int gid = blockIdx.x*256 + threadIdx.x;
  if (gid >= RR*EE) return;
  int r = gid / EE, e = gid - r*EE;
  int src = edges[(size_t)r*2*EE + e];
  int dst = edges[(size_t)r*2*EE + EE + e];
  int b = r*NBPR + (dst >> 8);
  int slot = boff[b] + atomicAdd(&bcur[b], 1);
  ebkt[slot] = ((unsigned)src << 8) | (unsigned)(dst & 255);
}

__global__ void k_bbuild(const unsigned* __restrict__ ebkt, const int* __restrict__ boff,
                         int* __restrict__ off, int* __restrict__ elist)
{
  __shared__ int cnt[256];
  __shared__ int sc[256];
  __shared__ int cur[256];
  int t = threadIdx.x;
  int bb = blockIdx.x;
  int e0 = boff[bb], e1 = boff[bb+1];
  cnt[t] = 0;
  __syncthreads();
  for (int i = e0 + t; i < e1; i += 256)
    atomicAdd(&cnt[ebkt[i] & 255u], 1);
  __syncthreads();
  sc[t] = cnt[t];
  __syncthreads();
  for (int o = 1; o < 256; o <<= 1) {
    int add = (t >= o) ? sc[t-o] : 0;
    __syncthreads();
    sc[t] += add;
    __syncthreads();
  }
  int excl = sc[t] - cnt[t];
  int r = bb / NBPR, b = bb - r*NBPR;
  int dst = b*256 + t;
  if (dst < NN) off[r*NN + dst] = e0 + excl;
  cur[t] = e0 + excl;
  __syncthreads();
  for (int i = e0 + t; i < e1; i += 256) {
    unsigned w = ebkt[i];
    int slot = atomicAdd(&cur[w & 255u], 1);
    elist[slot] = (int)(w >> 8);
  }
}

// ================= feature prep (bf16 hi/lo planes, K padded 21->32) =================
__global__ void k_featprep(const float* __restrict__ x_all, const float* __restrict__ pos_table,
                           short* __restrict__ x0h, short* __restrict__ x0l)
{
  int gid = blockIdx.x*256 + threadIdx.x;
  if (gid >= NN*32) return;
  int nidx = gid >> 5, c = gid & 31;
  float v = 0.f;
  if (c < 13) {
    int scl = (c < 5) ? c : c + 1;
    v = x_all[nidx*14 + scl];
  } else if (c < 21) {
    int pi = (int)x_all[nidx*14 + 5];
    pi = pi < 0 ? 0 : (pi > 23 ? 23 : pi);
    v = pos_table[pi*8 + (c - 13)];
  }
  unsigned short h = f2bf(v);
  unsigned short l = f2bf(v - bf2f(h));
  x0h[gid] = (short)h;
  x0l[gid] = (short)l;
}

// ================= weight prep: W[r][k][128] f32 -> Wt[r][n][KP] bf16 hi/lo =================
template<int KP>
__global__ void k_wprep(const float* __restrict__ W, int K,
                        short* __restrict__ Wh, short* __restrict__ Wl)
{
  int gid = blockIdx.x*256 + threadIdx.x;
  if (gid >= RR*128*KP) return;
  int r = gid / (128*KP);
  int rem = gid - r*(128*KP);
  int nn = rem / KP, k = rem - nn*KP;
  float v = (k < K) ? W[((size_t)r*K + k)*128 + nn] : 0.f;
  unsigned short h = f2bf(v);
  unsigned short l = f2bf(v - bf2f(h));
  Wh[gid] = (short)h;
  Wl[gid] = (short)l;
}

// ================= MFMA GEMM (split hi/lo bf16 ~ f32 accuracy) =================
// frag layout for mfma_f32_16x16x32_bf16: elem e of lane l -> k = 16*(e>>2) + 4*(l>>4) + (e&3)
__device__ __forceinline__ bf16x8 ldfrag_(const short* p, int row, int kb, int KP_, int smask)
{
  int xr = row & smask;
  int s0 = (((kb)      >> 3) ^ xr) * 8 + (kb & 7);
  int s1 = (((kb + 16) >> 3) ^ xr) * 8 + (kb & 7);
  bf16x4 a = *(const bf16x4*)(p + (size_t)row*KP_ + s0);
  bf16x4 b = *(const bf16x4*)(p + (size_t)row*KP_ + s1);
  return __builtin_shufflevector(a, b, 0,1,2,3,4,5,6,7);
}

template<int KP>
__global__ __launch_bounds__(256, 2)
void k_gemm_mfma(const short* __restrict__ Ah, const short* __restrict__ Al,
                 const short* __restrict__ Wh, const short* __restrict__ Wl,
                 const float* __restrict__ a_s, const float* __restrict__ a_d,
                 float* __restrict__ xp, float* __restrict__ zs, float* __restrict__ zd,
                 int n)
{
  constexpr int SLOTS = KP/8;
  constexpr int SMASK = (SLOTS >= 8) ? 7 : (SLOTS-1);
  __shared__ short lds[320*KP];   // A hi[32][KP], A lo, W hi[128][KP], W lo; reused as Cs[32][136] f32
  constexpr int AH0 = 0, AL0 = 32*KP, WH0 = 64*KP, WL0 = 192*KP;
  int tid = threadIdx.x;
  int r0 = blockIdx.x * 32;

  for (int ch = tid; ch < 32*SLOTS; ch += 256) {
    int row = ch / SLOTS, slot = ch - row*SLOTS;
    int gr = r0 + row;
    int dsl = (slot ^ (row & SMASK)) * 8;
    bf16x8 vh, vl;
    if (gr < n) {
      vh = *(const bf16x8*)(Ah + (size_t)gr*KP + slot*8);
      vl = *(const bf16x8*)(Al + (size_t)gr*KP + slot*8);
    } else {
      #pragma unroll
      for (int q = 0; q < 8; ++q) { vh[q] = 0; vl[q] = 0; }
    }
    *(bf16x8*)(lds + AH0 + row*KP + dsl) = vh;
    *(bf16x8*)(lds + AL0 + row*KP + dsl) = vl;
  }
  for (int ch = tid; ch < 128*SLOTS; ch += 256) {
    int row = ch / SLOTS, slot = ch - row*SLOTS;
    int dsl = (slot ^ (row & SMASK)) * 8;
    *(bf16x8*)(lds + WH0 + row*KP + dsl) = *(const bf16x8*)(Wh + (size_t)row*KP + slot*8);
    *(bf16x8*)(lds + WL0 + row*KP + dsl) = *(const bf16x8*)(Wl + (size_t)row*KP + slot*8);
  }
  __syncthreads();

  int wid = tid >> 6, lane = tid & 63;
  int lr = lane & 15, lg = lane >> 4;
  int rt = wid >> 1;
  int c0 = (wid & 1) * 4;
  f32x4 acc[4] = {{0,0,0,0},{0,0,0,0},{0,0,0,0},{0,0,0,0}};
  int arow = rt*16 + lr;

  #pragma unroll
  for (int kc = 0; kc < KP/32; ++kc) {
    int kb = kc*32 + 4*lg;
    bf16x8 ah = ldfrag_(lds + AH0, arow, kb, KP, SMASK);
    bf16x8 al = ldfrag_(lds + AL0, arow, kb, KP, SMASK);
    #pragma unroll
    for (int t = 0; t < 4; ++t) {
      int wrow = (c0 + t)*16 + lr;
      bf16x8 wh = ldfrag_(lds + WH0, wrow, kb, KP, SMASK);
      bf16x8 wl = ldfrag_(lds + WL0, wrow, kb, KP, SMASK);
      acc[t] = __builtin_amdgcn_mfma_f32_16x16x32_bf16(ah, wh, acc[t], 0, 0, 0);
      acc[t] = __builtin_amdgcn_mfma_f32_16x16x32_bf16(ah, wl, acc[t], 0, 0, 0);
      acc[t] = __builtin_amdgcn_mfma_f32_16x16x32_bf16(al, wh, acc[t], 0, 0, 0);
    }
  }
  __syncthreads();

  float* Cs = (float*)lds;   // [32][136]
  #pragma unroll
  for (int t = 0; t < 4; ++t)
    #pragma unroll
    for (int v = 0; v < 4; ++v) {
      int row = rt*16 + lg*4 + v;
      int col = (c0 + t)*16 + lr;
      Cs[row*136 + col] = acc[t][v];
    }
  __syncthreads();

  {
    int r = tid >> 3, sg = tid & 7;
    float ps = 0.f, pd = 0.f;
    #pragma unroll
    for (int i = 0; i < 16; ++i) {
      int c = sg*16 + i;
      float x = Cs[r*136 + c];
      ps = fmaf(x, a_s[c], ps);
      pd = fmaf(x, a_d[c], pd);
    }
    ps += __shfl_xor(ps, 1); pd += __shfl_xor(pd, 1);
    ps += __shfl_xor(ps, 2); pd += __shfl_xor(pd, 2);
    ps += __shfl_xor(ps, 4); pd += __shfl_xor(pd, 4);
    int gr = r0 + r;
    if (sg == 0 && gr < n) { zs[gr] = ps; zd[gr] = pd; }
  }
  for (int i = tid; i < 32*32; i += 256) {
    int row = i >> 5, q = i & 31;
    int gr = r0 + row;
    if (gr < n)
      *(float4*)(xp + (size_t)gr*128 + q*4) = *(const float4*)(Cs + row*136 + q*4);
  }
}

// ================= per-destination GAT aggregation =================
__global__ void k_agg(const float* __restrict__ xp, const float* __restrict__ zs,
                      const float* __restrict__ zd, const int* __restrict__ elist,
                      const int* __restrict__ off, float* __restrict__ hacc, int n)
{
  int wid = (int)((blockIdx.x*(size_t)blockDim.x + threadIdx.x) >> 6);
  int lane = threadIdx.x & 63;
  if (wid >= n) return;
  int o0 = off[wid], o1 = off[wid+1];
  int deg = o1 - o0;
  if (deg <= 0) return;
  float zdd = zd[wid];
  float m = -3.4e38f;
  for (int i = lane; i < deg; i += 64) {
    float z = zs[elist[o0+i]] + zdd;
    z = (z > 0.f) ? z : 0.2f*z;
    m = fmaxf(m, z);
  }
  #pragma unroll
  for (int o = 32; o > 0; o >>= 1) m = fmaxf(m, __shfl_xor(m, o));

  int h = lane >> 5, c = lane & 31;
  float a0=0.f, a1=0.f, a2=0.f, a3=0.f, esum=0.f;
  for (int base = 0; base < deg; base += 64) {
    int i = base + lane;
    float ew = 0.f; int s = 0;
    if (i < deg) {
      s = elist[o0+i];
      float z = zs[s] + zdd;
      z = (z > 0.f) ? z : 0.2f*z;
      ew = expf(z - m);
    }
    esum += ew;
    int cnt = min(64, deg - base);
    for (int t = 0; 2*t + h < cnt; ++t) {
      int j = 2*t + h;
      float w = __shfl(ew, j);
      int ss = __shfl(s, j);
      const float4 v = *(const float4*)(xp + (size_t)ss*128 + c*4);
      a0 = fmaf(w, v.x, a0); a1 = fmaf(w, v.y, a1);
      a2 = fmaf(w, v.z, a2); a3 = fmaf(w, v.w, a3);
    }
  }
  #pragma unroll
  for (int o = 32; o > 0; o >>= 1) esum += __shfl_xor(esum, o);
  a0 += __shfl_xor(a0, 32); a1 += __shfl_xor(a1, 32);
  a2 += __shfl_xor(a2, 32); a3 += __shfl_xor(a3, 32);
  if (h == 0) {
    float inv = 1.f / esum;
    float4* op = (float4*)(hacc + (size_t)wid*128 + c*4);
    float4 old = *op;
    old.x = fmaf(a0, inv, old.x);
    old.y = fmaf(a1, inv, old.y);
    old.z = fmaf(a2, inv, old.z);
    old.w = fmaf(a3, inv, old.w);
    *op = old;
  }
}

// ================= bias-sum =================
__global__ void k_bsum(const float* __restrict__ b, float* __restrict__ bs)
{
  int t = threadIdx.x;
  float s = 0.f;
  #pragma unroll
  for (int r = 0; r < RR; ++r) s += b[r*HH + t];
  bs[t] = s;
}

// ================= gelu(exact) + LayerNorm =================
// MODE 0: write bf16 hi/lo planes; MODE 1: write f32
template<int MODE>
__global__ void k_postln(const float* __restrict__ X, const float* __restrict__ bsum,
                         const float* __restrict__ nw, const float* __restrict__ nb,
                         short* __restrict__ Yh, short* __restrict__ Yl,
                         float* __restrict__ Yf, int n)
{
  int wid = (int)((blockIdx.x*(size_t)blockDim.x + threadIdx.x) >> 6);
  int lane = threadIdx.x & 63;
  if (wid >= n) return;
  float2 x = *(const float2*)(X + (size_t)wid*128 + lane*2);
  x.x += bsum[lane*2];
  x.y += bsum[lane*2+1];
  float g0 = 0.5f*x.x*(1.f + erff(x.x*0.70710678118654752f));
  float g1 = 0.5f*x.y*(1.f + erff(x.y*0.70710678118654752f));
  float s = g0 + g1;
  #pragma unroll
  for (int o = 32; o > 0; o >>= 1) s += __shfl_xor(s, o);
  float mu = s * (1.f/128.f);
  float d0 = g0 - mu, d1 = g1 - mu;
  float v = d0*d0 + d1*d1;
  #pragma unroll
  for (int o = 32; o > 0; o >>= 1) v += __shfl_xor(v, o);
  v *= (1.f/128.f);
  float inv = 1.f / sqrtf(v + 1e-5f);
  float y0 = d0*inv*nw[lane*2]   + nb[lane*2];
  float y1 = d1*inv*nw[lane*2+1] + nb[lane*2+1];
  if (MODE == 0) {
    unsigned short h0 = f2bf(y0), h1 = f2bf(y1);
    unsigned short l0 = f2bf(y0 - bf2f(h0)), l1 = f2bf(y1 - bf2f(h1));
    short2 hh; hh.x = (short)h0; hh.y = (short)h1;
    short2 ll; ll.x = (short)l0; ll.y = (short)l1;
    *(short2*)(Yh + (size_t)wid*128 + lane*2) = hh;
    *(short2*)(Yl + (size_t)wid*128 + lane*2) = ll;
  } else {
    float2 y; y.x = y0; y.y = y1;
    *(float2*)(Yf + (size_t)wid*128 + lane*2) = y;
  }
}

// ================= pooling =================
__global__ void k_score(const float* __restrict__ X, const float* __restrict__ q,
                        const int* __restrict__ batch, float* __restrict__ scores,
                        unsigned* __restrict__ bmax, int n)
{
  int wid = (int)((blockIdx.x*(size_t)blockDim.x + threadIdx.x) >> 6);
  int lane = threadIdx.x & 63;
  if (wid >= n) return;
  float2 x = *(const float2*)(X + (size_t)wid*128 + lane*2);
  float s = x.x*q[lane*2] + x.y*q[lane*2+1];
  #pragma unroll
  for (int o = 32; o > 0; o >>= 1) s += __shfl_xor(s, o);
  if (lane == 0) {
    scores[wid] = s;
    atomicMax(&bmax[batch[wid]], fenc(s));
  }
}

__global__ void k_segbounds(const int* __restrict__ batch, int* __restrict__ segst,
                            int n, int numB)
{
  int b = blockIdx.x*256 + threadIdx.x;
  if (b > numB) return;
  int lo = 0, hi = n;
  while (lo < hi) { int mid = (lo+hi) >> 1; if (batch[mid] < b) lo = mid+1; else hi = mid; }
  segst[b] = lo;
}

__global__ void k_pool(const float* __restrict__ X, const float* __restrict__ scores,
                       const int* __restrict__ segst, const unsigned* __restrict__ bmax,
                       float* __restrict__ pool, int numB)
{
  int b = blockIdx.x;
  int t = threadIdx.x;
  int s0 = segst[b], s1 = segst[b+1];
  float m = fdec(bmax[b]);
  float acc = 0.f, esum = 0.f;
  for (int i = s0; i < s1; ++i) {
    float e = expf(scores[i] - m);
    esum += e;
    acc = fmaf(e, X[(size_t)i*128 + t], acc);
  }
  float inv = (s1 > s0) ? 1.f/esum : 0.f;
  pool[(size_t)b*128 + t] = acc * inv;
}

__global__ void k_outgemm(const float* __restrict__ pool, const float* __restrict__ projW,
                          const float* __restrict__ projb, float* __restrict__ out, int numB)
{
  int b = blockIdx.x;
  int j = threadIdx.x;
  __shared__ float p[128];
  p[j] = pool[(size_t)b*128 + j];
  __syncthreads();
  float acc = projb[j];
  #pragma unroll 16
  for (int k = 0; k < 128; ++k) acc = fmaf(p[k], projW[(size_t)k*128 + j], acc);
  out[(size_t)b*128 + j] = acc;
}

// ================= launcher =================
extern "C" void kernel_launch(void* const* d_in, const int* in_sizes, int n_in,
                              void* d_out, int out_size, void* d_ws, size_t ws_size,
                              hipStream_t stream)
{
  const float* x_all = (const float*)d_in[0];
  const int*   edges = (const int*)d_in[1];
  const int*   batch = (const int*)d_in[2];
  const float* pos_table = (const float*)d_in[3];
  const float* W1  = (const float*)d_in[4];
  const float* as1 = (const float*)d_in[5];
  const float* ad1 = (const float*)d_in[6];
  const float* b1  = (const float*)d_in[7];
  const float* W2  = (const float*)d_in[8];
  const float* as2 = (const float*)d_in[9];
  const float* ad2 = (const float*)d_in[10];
  const float* b2  = (const float*)d_in[11];
  const float* n1w = (const float*)d_in[12];
  const float* n1b = (const float*)d_in[13];
  const float* n2w = (const float*)d_in[14];
  const float* n2b = (const float*)d_in[15];
  const float* query = (const float*)d_in[16];
  const float* projW = (const float*)d_in[17];
  const float* projb = (const float*)d_in[18];
  float* out = (float*)d_out;
  (void)in_sizes; (void)n_in; (void)out_size; (void)ws_size;

  char* p = (char*)d_ws;
  auto alloc = [&](size_t b){ void* r = (void*)p; p += (b + 255) & ~(size_t)255; return r; };
  int*   off   = (int*)alloc((size_t)(MM+1)*sizeof(int));
  int*   elist = (int*)alloc((size_t)RR*EE*sizeof(int));
  int*   bcnt  = (int*)alloc((size_t)NBK*sizeof(int));
  int*   boff  = (int*)alloc((size_t)(NBK+1)*sizeof(int));
  int*   bcur  = (int*)alloc((size_t)NBK*sizeof(int));
  short* wtH   = (short*)alloc((size_t)RR*128*128*sizeof(short));
  short* wtL   = (short*)alloc((size_t)RR*128*128*sizeof(short));
  float* zs    = (float*)alloc((size_t)NN*sizeof(float));
  float* zd    = (float*)alloc((size_t)NN*sizeof(float));
  float* bsv   = (float*)alloc(128*sizeof(float));
  int*   segst = (int*)alloc((size_t)(BB+1)*sizeof(int));
  unsigned* bmax = (unsigned*)alloc((size_t)BB*sizeof(unsigned));
  float* pool  = (float*)alloc((size_t)BB*HH*sizeof(float));
  float* bigA  = (float*)alloc((size_t)NN*128*sizeof(float));  // x0 planes, then h1 planes
  float* bigB  = (float*)alloc((size_t)NN*128*sizeof(float));  // xp f32, then h2 f32
  float* bigC  = (float*)alloc((size_t)NN*128*sizeof(float));  // ebkt (front 19.2MB), then hacc

  short* x0h = (short*)bigA;                      // [N][32]
  short* x0l = (short*)bigA + (size_t)NN*32;
  short* h1h = (short*)bigA;                      // [N][128] (x0 dead by then)
  short* h1l = (short*)bigA + (size_t)NN*128;
  float* xp   = bigB;
  float* h2   = bigB;                             // alias (xp dead by then)
  unsigned* ebkt = (unsigned*)bigC;               // [RR*EE] (dead before hacc memset)
  float* hacc = bigC;

  // --- CSR build (bucketed) ---
  hipMemsetAsync(bcnt, 0, (size_t)NBK*sizeof(int), stream);
  hipMemsetAsync(bcur, 0, (size_t)NBK*sizeof(int), stream);
  k_bcount<<<ceil_div(RR*EE,256),256,0,stream>>>(edges, bcnt);
  k_bscan<<<1,256,0,stream>>>(bcnt, boff, off);
  k_bscatter<<<ceil_div(RR*EE,256),256,0,stream>>>(edges, boff, bcur, ebkt);
  k_bbuild<<<NBK,256,0,stream>>>(ebkt, boff, off, elist);

  // --- feature prep ---
  k_featprep<<<ceil_div(NN*32,256),256,0,stream>>>(x_all, pos_table, x0h, x0l);

  // --- layer 1 ---
  k_wprep<32><<<ceil_div(RR*128*32,256),256,0,stream>>>(W1, 21, wtH, wtL);
  hipMemsetAsync(hacc, 0, (size_t)NN*128*sizeof(float), stream);
  for (int r = 0; r < RR; ++r) {
    k_gemm_mfma<32><<<ceil_div(NN,32),256,0,stream>>>(
        x0h, x0l, wtH + (size_t)r*128*32, wtL + (size_t)r*128*32,
        as1 + r*HH, ad1 + r*HH, xp, zs, zd, NN);
    k_agg<<<ceil_div(NN*64,256),256,0,stream>>>(xp, zs, zd, elist, off + r*NN, hacc, NN);
  }
  k_bsum<<<1,128,0,stream>>>(b1, bsv);
  k_postln<0><<<ceil_div(NN*64,256),256,0,stream>>>(hacc, bsv, n1w, n1b, h1h, h1l, (float*)0, NN);

  // --- layer 2 ---
  k_wprep<128><<<ceil_div(RR*128*128,256),256,0,stream>>>(W2, 128, wtH, wtL);
  hipMemsetAsync(hacc, 0, (size_t)NN*128*sizeof(float), stream);
  for (int r = 0; r < RR; ++r) {
    k_gemm_mfma<128><<<ceil_div(NN,32),256,0,stream>>>(
        h1h, h1l, wtH + (size_t)r*128*128, wtL + (size_t)r*128*128,
        as2 + r*HH, ad2 + r*HH, xp, zs, zd, NN);
    k_agg<<<ceil_div(NN*64,256),256,0,stream>>>(xp, zs, zd, elist, off + r*NN, hacc, NN);
  }
  k_bsum<<<1,128,0,stream>>>(b2, bsv);
  k_postln<1><<<ceil_div(NN*64,256),256,0,stream>>>(hacc, bsv, n2w, n2b, (short*)0, (short*)0, h2, NN);

  // --- attention pooling ---
  hipMemsetAsync(bmax, 0, (size_t)BB*sizeof(unsigned), stream);
  k_score<<<ceil_div(NN*64,256),256,0,stream>>>(h2, query, batch, zs, bmax, NN);
  k_segbounds<<<ceil_div(BB+1,256),256,0,stream>>>(batch, segst, NN, BB);
  k_pool<<<BB,128,0,stream>>>(h2, zs, segst, bmax, pool, BB);
  k_outgemm<<<BB,128,0,stream>>>(pool, projW, projb, out, BB);
}

// Round 3
// 1674.836 us; speedup vs baseline: 1.8860x; 1.8860x over previous
//
#include <hip/hip_runtime.h>
#include <math.h>

#define NN   100000
#define EE   800000
#define RR   6
#define BB   1000
#define HH   128
#define MM   (RR*NN)
#define NBPR ((NN + 255) >> 8)       // 391 buckets per relation (256 dst each)
#define NBK  (RR * NBPR)             // 2346
#define CH   4096                    // edges per binning chunk

static inline int ceil_div(int a, int b){ return (a+b-1)/b; }

typedef __attribute__((ext_vector_type(8))) short bf16x8;
typedef __attribute__((ext_vector_type(4))) short bf16x4;
typedef __attribute__((ext_vector_type(4))) float f32x4;

__device__ __forceinline__ unsigned fenc(float f){
  unsigned u = __float_as_uint(f);
  return (u & 0x80000000u) ? ~u : (u | 0x80000000u);
}
__device__ __forceinline__ float fdec(unsigned u){
  return __uint_as_float((u & 0x80000000u) ? (u & 0x7fffffffu) : ~u);
}
__device__ __forceinline__ unsigned short f2bf(float f){
  unsigned u = __float_as_uint(f);
  return (unsigned short)((u + 0x7fffu + ((u >> 16) & 1u)) >> 16);
}
__device__ __forceinline__ float bf2f(unsigned short h){
  return __uint_as_float(((unsigned)h) << 16);
}

// ================= bucketed CSR build (LDS-histogram binning) =================
// WG handles CH contiguous edges of one relation; LDS hist over 391 buckets;
// one global atomic per touched bucket per WG (not per edge).
__global__ void k_bcount(const int* __restrict__ edges, int* __restrict__ bcnt)
{
  __shared__ int hist[NBPR];
  int t = threadIdx.x;
  const int nch = (EE + CH - 1) / CH;
  int r = blockIdx.x / nch, c = blockIdx.x - r*nch;
  for (int i = t; i < NBPR; i += 256) hist[i] = 0;
  __syncthreads();
  const int* dptr = edges + (size_t)r*2*EE + EE;
  int e0 = c*CH, e1 = min(EE, e0 + CH);
  for (int i = e0 + t; i < e1; i += 256)
    atomicAdd(&hist[dptr[i] >> 8], 1);
  __syncthreads();
  for (int i = t; i < NBPR; i += 256) {
    int h = hist[i];
    if (h) atomicAdd(&bcnt[r*NBPR + i], h);
  }
}

__global__ void k_bscan(const int* __restrict__ bcnt, int* __restrict__ boff,
                        int* __restrict__ off)
{
  __shared__ int sh[256];
  int t = threadIdx.x;
  int carry = 0;
  for (int c = 0; c < NBK; c += 256) {
    int idx = c + t;
    int v = (idx < NBK) ? bcnt[idx] : 0;
    sh[t] = v;
    __syncthreads();
    for (int o = 1; o < 256; o <<= 1) {
      int add = (t >= o) ? sh[t-o] : 0;
      __syncthreads();
      sh[t] += add;
      __syncthreads();
    }
    int incl = sh[t];
    int tot  = sh[255];
    if (idx < NBK) boff[idx] = carry + incl - v;
    __syncthreads();
    carry += tot;
  }
  if (t == 0) { boff[NBK] = carry; off[MM] = carry; }
}

__global__ void k_binscatter(const int* __restrict__ edges, int* __restrict__ bcur,
                             unsigned* __restrict__ ebkt)
{
  __shared__ int hist[NBPR];
  __shared__ int base[NBPR];
  int t = threadIdx.x;
  const int nch = (EE + CH - 1) / CH;
  int r = blockIdx.x / nch, c = blockIdx.x - r*nch;
  for (int i = t; i < NBPR; i += 256) hist[i] = 0;
  __syncthreads();
  const int* sptr = edges + (size_t)r*2*EE;
  const int* dptr = sptr + EE;
  int e0 = c*CH, e1 = min(EE, e0 + CH);
  for (int i = e0 + t; i < e1; i += 256)
    atomicAdd(&hist[dptr[i] >> 8], 1);
  __syncthreads();
  for (int i = t; i < NBPR; i += 256) {
    int h = hist[i];
    base[i] = h ? atomicAdd(&bcur[r*NBPR + i], h) : 0;
    hist[i] = 0;
  }
  __syncthreads();
  for (int i = e0 + t; i < e1; i += 256) {
    int dst = dptr[i];
    int b = dst >> 8;
    int slot = base[b] + atomicAdd(&hist[b], 1);
    ebkt[slot] = ((unsigned)sptr[i] << 8) | (unsigned)(dst & 255);
  }
}

__global__ void k_bbuild(const unsigned* __restrict__ ebkt, const int* __restrict__ boff,
                         int* __restrict__ off, int* __restrict__ elist)
{
  __shared__ int cnt[256];
  __shared__ int sc[256];
  __shared__ int cur[256];
  int t = threadIdx.x;
  int bb = blockIdx.x;
  int e0 = boff[bb], e1 = boff[bb+1];
  cnt[t] = 0;
  __syncthreads();
  for (int i = e0 + t; i < e1; i += 256)
    atomicAdd(&cnt[ebkt[i] & 255u], 1);
  __syncthreads();
  sc[t] = cnt[t];
  __syncthreads();
  for (int o = 1; o < 256; o <<= 1) {
    int add = (t >= o) ? sc[t-o] : 0;
    __syncthreads();
    sc[t] += add;
    __syncthreads();
  }
  int excl = sc[t] - cnt[t];
  int r = bb / NBPR, b = bb - r*NBPR;
  int dst = b*256 + t;
  if (dst < NN) off[r*NN + dst] = e0 + excl;
  cur[t] = e0 + excl;
  __syncthreads();
  for (int i = e0 + t; i < e1; i += 256) {
    unsigned w = ebkt[i];
    int slot = atomicAdd(&cur[w & 255u], 1);
    elist[slot] = (int)(w >> 8);
  }
}

// ================= feature prep (bf16 hi/lo planes, K padded 21->32) =================
__global__ void k_featprep(const float* __restrict__ x_all, const float* __restrict__ pos_table,
                           short* __restrict__ x0h, short* __restrict__ x0l)
{
  int gid = blockIdx.x*256 + threadIdx.x;
  if (gid >= NN*32) return;
  int nidx = gid >> 5, c = gid & 31;
  float v = 0.f;
  if (c < 13) {
    int scl = (c < 5) ? c : c + 1;
    v = x_all[nidx*14 + scl];
  } else if (c < 21) {
    int pi = (int)x_all[nidx*14 + 5];
    pi = pi < 0 ? 0 : (pi > 23 ? 23 : pi);
    v = pos_table[pi*8 + (c - 13)];
  }
  unsigned short h = f2bf(v);
  unsigned short l = f2bf(v - bf2f(h));
  x0h[gid] = (short)h;
  x0l[gid] = (short)l;
}

// ================= weight prep: W[r][k][128] f32 -> Wt[r][n][KP] bf16 hi/lo =================
template<int KP>
__global__ void k_wprep(const float* __restrict__ W, int K,
                        short* __restrict__ Wh, short* __restrict__ Wl)
{
  int gid = blockIdx.x*256 + threadIdx.x;
  if (gid >= RR*128*KP) return;
  int r = gid / (128*KP);
  int rem = gid - r*(128*KP);
  int nn = rem / KP, k = rem - nn*KP;
  float v = (k < K) ? W[((size_t)r*K + k)*128 + nn] : 0.f;
  unsigned short h = f2bf(v);
  unsigned short l = f2bf(v - bf2f(h));
  Wh[gid] = (short)h;
  Wl[gid] = (short)l;
}

// ================= MFMA GEMM (split hi/lo bf16 ~ f32 accuracy) =================
__device__ __forceinline__ bf16x8 ldfrag_(const short* p, int row, int kb, int KP_, int smask)
{
  int xr = row & smask;
  int s0 = (((kb)      >> 3) ^ xr) * 8 + (kb & 7);
  int s1 = (((kb + 16) >> 3) ^ xr) * 8 + (kb & 7);
  bf16x4 a = *(const bf16x4*)(p + (size_t)row*KP_ + s0);
  bf16x4 b = *(const bf16x4*)(p + (size_t)row*KP_ + s1);
  return __builtin_shufflevector(a, b, 0,1,2,3,4,5,6,7);
}

template<int KP>
__global__ __launch_bounds__(256, 2)
void k_gemm_mfma(const short* __restrict__ Ah, const short* __restrict__ Al,
                 const short* __restrict__ Wh, const short* __restrict__ Wl,
                 const float* __restrict__ a_s, const float* __restrict__ a_d,
                 float* __restrict__ xp, float* __restrict__ zs, float* __restrict__ zd,
                 int n)
{
  constexpr int SLOTS = KP/8;
  constexpr int SMASK = (SLOTS >= 8) ? 7 : (SLOTS-1);
  __shared__ short lds[320*KP];
  constexpr int AH0 = 0, AL0 = 32*KP, WH0 = 64*KP, WL0 = 192*KP;
  int tid = threadIdx.x;
  int r0 = blockIdx.x * 32;

  for (int ch = tid; ch < 32*SLOTS; ch += 256) {
    int row = ch / SLOTS, slot = ch - row*SLOTS;
    int gr = r0 + row;
    int dsl = (slot ^ (row & SMASK)) * 8;
    bf16x8 vh, vl;
    if (gr < n) {
      vh = *(const bf16x8*)(Ah + (size_t)gr*KP + slot*8);
      vl = *(const bf16x8*)(Al + (size_t)gr*KP + slot*8);
    } else {
      #pragma unroll
      for (int q = 0; q < 8; ++q) { vh[q] = 0; vl[q] = 0; }
    }
    *(bf16x8*)(lds + AH0 + row*KP + dsl) = vh;
    *(bf16x8*)(lds + AL0 + row*KP + dsl) = vl;
  }
  for (int ch = tid; ch < 128*SLOTS; ch += 256) {
    int row = ch / SLOTS, slot = ch - row*SLOTS;
    int dsl = (slot ^ (row & SMASK)) * 8;
    *(bf16x8*)(lds + WH0 + row*KP + dsl) = *(const bf16x8*)(Wh + (size_t)row*KP + slot*8);
    *(bf16x8*)(lds + WL0 + row*KP + dsl) = *(const bf16x8*)(Wl + (size_t)row*KP + slot*8);
  }
  __syncthreads();

  int wid = tid >> 6, lane = tid & 63;
  int lr = lane & 15, lg = lane >> 4;
  int rt = wid >> 1;
  int c0 = (wid & 1) * 4;
  f32x4 acc[4] = {{0,0,0,0},{0,0,0,0},{0,0,0,0},{0,0,0,0}};
  int arow = rt*16 + lr;

  #pragma unroll
  for (int kc = 0; kc < KP/32; ++kc) {
    int kb = kc*32 + 4*lg;
    bf16x8 ah = ldfrag_(lds + AH0, arow, kb, KP, SMASK);
    bf16x8 al = ldfrag_(lds + AL0, arow, kb, KP, SMASK);
    #pragma unroll
    for (int t = 0; t < 4; ++t) {
      int wrow = (c0 + t)*16 + lr;
      bf16x8 wh = ldfrag_(lds + WH0, wrow, kb, KP, SMASK);
      bf16x8 wl = ldfrag_(lds + WL0, wrow, kb, KP, SMASK);
      acc[t] = __builtin_amdgcn_mfma_f32_16x16x32_bf16(ah, wh, acc[t], 0, 0, 0);
      acc[t] = __builtin_amdgcn_mfma_f32_16x16x32_bf16(ah, wl, acc[t], 0, 0, 0);
      acc[t] = __builtin_amdgcn_mfma_f32_16x16x32_bf16(al, wh, acc[t], 0, 0, 0);
    }
  }
  __syncthreads();

  float* Cs = (float*)lds;   // [32][136]
  #pragma unroll
  for (int t = 0; t < 4; ++t)
    #pragma unroll
    for (int v = 0; v < 4; ++v) {
      int row = rt*16 + lg*4 + v;
      int col = (c0 + t)*16 + lr;
      Cs[row*136 + col] = acc[t][v];
    }
  __syncthreads();

  {
    int r = tid >> 3, sg = tid & 7;
    float ps = 0.f, pd = 0.f;
    #pragma unroll
    for (int i = 0; i < 16; ++i) {
      int c = sg*16 + i;
      float x = Cs[r*136 + c];
      ps = fmaf(x, a_s[c], ps);
      pd = fmaf(x, a_d[c], pd);
    }
    ps += __shfl_xor(ps, 1); pd += __shfl_xor(pd, 1);
    ps += __shfl_xor(ps, 2); pd += __shfl_xor(pd, 2);
    ps += __shfl_xor(ps, 4); pd += __shfl_xor(pd, 4);
    int gr = r0 + r;
    if (sg == 0 && gr < n) { zs[gr] = ps; zd[gr] = pd; }
  }
  for (int i = tid; i < 32*32; i += 256) {
    int row = i >> 5, q = i & 31;
    int gr = r0 + row;
    if (gr < n)
      *(float4*)(xp + (size_t)gr*128 + q*4) = *(const float4*)(Cs + row*136 + q*4);
  }
}

// ================= per-destination GAT aggregation =================
__global__ void k_agg(const float* __restrict__ xp, const float* __restrict__ zs,
                      const float* __restrict__ zd, const int* __restrict__ elist,
                      const int* __restrict__ off, float* __restrict__ hacc, int n)
{
  int wid = (int)((blockIdx.x*(size_t)blockDim.x + threadIdx.x) >> 6);
  int lane = threadIdx.x & 63;
  if (wid >= n) return;
  int o0 = off[wid], o1 = off[wid+1];
  int deg = o1 - o0;
  if (deg <= 0) return;
  float zdd = zd[wid];
  float m = -3.4e38f;
  for (int i = lane; i < deg; i += 64) {
    float z = zs[elist[o0+i]] + zdd;
    z = (z > 0.f) ? z : 0.2f*z;
    m = fmaxf(m, z);
  }
  #pragma unroll
  for (int o = 32; o > 0; o >>= 1) m = fmaxf(m, __shfl_xor(m, o));

  int h = lane >> 5, c = lane & 31;
  float a0=0.f, a1=0.f, a2=0.f, a3=0.f, esum=0.f;
  for (int base = 0; base < deg; base += 64) {
    int i = base + lane;
    float ew = 0.f; int s = 0;
    if (i < deg) {
      s = elist[o0+i];
      float z = zs[s] + zdd;
      z = (z > 0.f) ? z : 0.2f*z;
      ew = expf(z - m);
    }
    esum += ew;
    int cnt = min(64, deg - base);
    for (int t = 0; 2*t + h < cnt; ++t) {
      int j = 2*t + h;
      float w = __shfl(ew, j);
      int ss = __shfl(s, j);
      const float4 v = *(const float4*)(xp + (size_t)ss*128 + c*4);
      a0 = fmaf(w, v.x, a0); a1 = fmaf(w, v.y, a1);
      a2 = fmaf(w, v.z, a2); a3 = fmaf(w, v.w, a3);
    }
  }
  #pragma unroll
  for (int o = 32; o > 0; o >>= 1) esum += __shfl_xor(esum, o);
  a0 += __shfl_xor(a0, 32); a1 += __shfl_xor(a1, 32);
  a2 += __shfl_xor(a2, 32); a3 += __shfl_xor(a3, 32);
  if (h == 0) {
    float inv = 1.f / esum;
    float4* op = (float4*)(hacc + (size_t)wid*128 + c*4);
    float4 old = *op;
    old.x = fmaf(a0, inv, old.x);
    old.y = fmaf(a1, inv, old.y);
    old.z = fmaf(a2, inv, old.z);
    old.w = fmaf(a3, inv, old.w);
    *op = old;
  }
}

// ================= bias-sum =================
__global__ void k_bsum(const float* __restrict__ b, float* __restrict__ bs)
{
  int t = threadIdx.x;
  float s = 0.f;
  #pragma unroll
  for (int r = 0; r < RR; ++r) s += b[r*HH + t];
  bs[t] = s;
}

// ================= gelu(exact) + LayerNorm =================
template<int MODE>
__global__ void k_postln(const float* __restrict__ X, const float* __restrict__ bsum,
                         const float* __restrict__ nw, const float* __restrict__ nb,
                         short* __restrict__ Yh, short* __restrict__ Yl,
                         float* __restrict__ Yf, int n)
{
  int wid = (int)((blockIdx.x*(size_t)blockDim.x + threadIdx.x) >> 6);
  int lane = threadIdx.x & 63;
  if (wid >= n) return;
  float2 x = *(const float2*)(X + (size_t)wid*128 + lane*2);
  x.x += bsum[lane*2];
  x.y += bsum[lane*2+1];
  float g0 = 0.5f*x.x*(1.f + erff(x.x*0.70710678118654752f));
  float g1 = 0.5f*x.y*(1.f + erff(x.y*0.70710678118654752f));
  float s = g0 + g1;
  #pragma unroll
  for (int o = 32; o > 0; o >>= 1) s += __shfl_xor(s, o);
  float mu = s * (1.f/128.f);
  float d0 = g0 - mu, d1 = g1 - mu;
  float v = d0*d0 + d1*d1;
  #pragma unroll
  for (int o = 32; o > 0; o >>= 1) v += __shfl_xor(v, o);
  v *= (1.f/128.f);
  float inv = 1.f / sqrtf(v + 1e-5f);
  float y0 = d0*inv*nw[lane*2]   + nb[lane*2];
  float y1 = d1*inv*nw[lane*2+1] + nb[lane*2+1];
  if (MODE == 0) {
    unsigned short h0 = f2bf(y0), h1 = f2bf(y1);
    unsigned short l0 = f2bf(y0 - bf2f(h0)), l1 = f2bf(y1 - bf2f(h1));
    short2 hh; hh.x = (short)h0; hh.y = (short)h1;
    short2 ll; ll.x = (short)l0; ll.y = (short)l1;
    *(short2*)(Yh + (size_t)wid*128 + lane*2) = hh;
    *(short2*)(Yl + (size_t)wid*128 + lane*2) = ll;
  } else {
    float2 y; y.x = y0; y.y = y1;
    *(float2*)(Yf + (size_t)wid*128 + lane*2) = y;
  }
}

// ================= pooling =================
__global__ void k_score(const float* __restrict__ X, const float* __restrict__ q,
                        const int* __restrict__ batch, float* __restrict__ scores,
                        unsigned* __restrict__ bmax, int n)
{
  int wid = (int)((blockIdx.x*(size_t)blockDim.x + threadIdx.x) >> 6);
  int lane = threadIdx.x & 63;
  if (wid >= n) return;
  float2 x = *(const float2*)(X + (size_t)wid*128 + lane*2);
  float s = x.x*q[lane*2] + x.y*q[lane*2+1];
  #pragma unroll
  for (int o = 32; o > 0; o >>= 1) s += __shfl_xor(s, o);
  if (lane == 0) {
    scores[wid] = s;
    atomicMax(&bmax[batch[wid]], fenc(s));
  }
}

__global__ void k_segbounds(const int* __restrict__ batch, int* __restrict__ segst,
                            int n, int numB)
{
  int b = blockIdx.x*256 + threadIdx.x;
  if (b > numB) return;
  int lo = 0, hi = n;
  while (lo < hi) { int mid = (lo+hi) >> 1; if (batch[mid] < b) lo = mid+1; else hi = mid; }
  segst[b] = lo;
}

__global__ void k_pool(const float* __restrict__ X, const float* __restrict__ scores,
                       const int* __restrict__ segst, const unsigned* __restrict__ bmax,
                       float* __restrict__ pool, int numB)
{
  int b = blockIdx.x;
  int t = threadIdx.x;
  int s0 = segst[b], s1 = segst[b+1];
  float m = fdec(bmax[b]);
  float acc = 0.f, esum = 0.f;
  for (int i = s0; i < s1; ++i) {
    float e = expf(scores[i] - m);
    esum += e;
    acc = fmaf(e, X[(size_t)i*128 + t], acc);
  }
  float inv = (s1 > s0) ? 1.f/esum : 0.f;
  pool[(size_t)b*128 + t] = acc * inv;
}

__global__ void k_outgemm(const float* __restrict__ pool, const float* __restrict__ projW,
                          const float* __restrict__ projb, float* __restrict__ out, int numB)
{
  int b = blockIdx.x;
  int j = threadIdx.x;
  __shared__ float p[128];
  p[j] = pool[(size_t)b*128 + j];
  __syncthreads();
  float acc = projb[j];
  #pragma unroll 16
  for (int k = 0; k < 128; ++k) acc = fmaf(p[k], projW[(size_t)k*128 + j], acc);
  out[(size_t)b*128 + j] = acc;
}

// ================= launcher =================
extern "C" void kernel_launch(void* const* d_in, const int* in_sizes, int n_in,
                              void* d_out, int out_size, void* d_ws, size_t ws_size,
                              hipStream_t stream)
{
  const float* x_all = (const float*)d_in[0];
  const int*   edges = (const int*)d_in[1];
  const int*   batch = (const int*)d_in[2];
  const float* pos_table = (const float*)d_in[3];
  const float* W1  = (const float*)d_in[4];
  const float* as1 = (const float*)d_in[5];
  const float* ad1 = (const float*)d_in[6];
  const float* b1  = (const float*)d_in[7];
  const float* W2  = (const float*)d_in[8];
  const float* as2 = (const float*)d_in[9];
  const float* ad2 = (const float*)d_in[10];
  const float* b2  = (const float*)d_in[11];
  const float* n1w = (const float*)d_in[12];
  const float* n1b = (const float*)d_in[13];
  const float* n2w = (const float*)d_in[14];
  const float* n2b = (const float*)d_in[15];
  const float* query = (const float*)d_in[16];
  const float* projW = (const float*)d_in[17];
  const float* projb = (const float*)d_in[18];
  float* out = (float*)d_out;
  (void)in_sizes; (void)n_in; (void)out_size; (void)ws_size;

  char* p = (char*)d_ws;
  auto alloc = [&](size_t b){ void* r = (void*)p; p += (b + 255) & ~(size_t)255; return r; };
  int*   off   = (int*)alloc((size_t)(MM+1)*sizeof(int));
  int*   elist = (int*)alloc((size_t)RR*EE*sizeof(int));
  int*   bcnt  = (int*)alloc((size_t)NBK*sizeof(int));
  int*   boff  = (int*)alloc((size_t)(NBK+1)*sizeof(int));
  int*   bcur  = (int*)alloc((size_t)NBK*sizeof(int));
  short* wtH   = (short*)alloc((size_t)RR*128*128*sizeof(short));
  short* wtL   = (short*)alloc((size_t)RR*128*128*sizeof(short));
  float* zs    = (float*)alloc((size_t)NN*sizeof(float));
  float* zd    = (float*)alloc((size_t)NN*sizeof(float));
  float* bsv   = (float*)alloc(128*sizeof(float));
  int*   segst = (int*)alloc((size_t)(BB+1)*sizeof(int));
  unsigned* bmax = (unsigned*)alloc((size_t)BB*sizeof(unsigned));
  float* pool  = (float*)alloc((size_t)BB*HH*sizeof(float));
  float* bigA  = (float*)alloc((size_t)NN*128*sizeof(float));  // x0 planes, then h1 planes
  float* bigB  = (float*)alloc((size_t)NN*128*sizeof(float));  // xp f32, then h2 f32
  float* bigC  = (float*)alloc((size_t)NN*128*sizeof(float));  // ebkt (front 19.2MB), then hacc

  short* x0h = (short*)bigA;                      // [N][32]
  short* x0l = (short*)bigA + (size_t)NN*32;
  short* h1h = (short*)bigA;                      // [N][128] (x0 dead by then)
  short* h1l = (short*)bigA + (size_t)NN*128;
  float* xp   = bigB;
  float* h2   = bigB;                             // alias (xp dead by then)
  unsigned* ebkt = (unsigned*)bigC;               // [RR*EE] (dead before hacc memset)
  float* hacc = bigC;

  // --- CSR build (LDS-histogram binning, low-contention) ---
  const int nch = (EE + CH - 1) / CH;
  hipMemsetAsync(bcnt, 0, (size_t)NBK*sizeof(int), stream);
  k_bcount<<<RR*nch,256,0,stream>>>(edges, bcnt);
  k_bscan<<<1,256,0,stream>>>(bcnt, boff, off);
  hipMemcpyAsync(bcur, boff, (size_t)NBK*sizeof(int), hipMemcpyDeviceToDevice, stream);
  k_binscatter<<<RR*nch,256,0,stream>>>(edges, bcur, ebkt);
  k_bbuild<<<NBK,256,0,stream>>>(ebkt, boff, off, elist);

  // --- feature prep ---
  k_featprep<<<ceil_div(NN*32,256),256,0,stream>>>(x_all, pos_table, x0h, x0l);

  // --- layer 1 ---
  k_wprep<32><<<ceil_div(RR*128*32,256),256,0,stream>>>(W1, 21, wtH, wtL);
  hipMemsetAsync(hacc, 0, (size_t)NN*128*sizeof(float), stream);
  for (int r = 0; r < RR; ++r) {
    k_gemm_mfma<32><<<ceil_div(NN,32),256,0,stream>>>(
        x0h, x0l, wtH + (size_t)r*128*32, wtL + (size_t)r*128*32,
        as1 + r*HH, ad1 + r*HH, xp, zs, zd, NN);
    k_agg<<<ceil_div(NN*64,256),256,0,stream>>>(xp, zs, zd, elist, off + r*NN, hacc, NN);
  }
  k_bsum<<<1,128,0,stream>>>(b1, bsv);
  k_postln<0><<<ceil_div(NN*64,256),256,0,stream>>>(hacc, bsv, n1w, n1b, h1h, h1l, (float*)0, NN);

  // --- layer 2 ---
  k_wprep<128><<<ceil_div(RR*128*128,256),256,0,stream>>>(W2, 128, wtH, wtL);
  hipMemsetAsync(hacc, 0, (size_t)NN*128*sizeof(float), stream);
  for (int r = 0; r < RR; ++r) {
    k_gemm_mfma<128><<<ceil_div(NN,32),256,0,stream>>>(
        h1h, h1l, wtH + (size_t)r*128*128, wtL + (size_t)r*128*128,
        as2 + r*HH, ad2 + r*HH, xp, zs, zd, NN);
    k_agg<<<ceil_div(NN*64,256),256,0,stream>>>(xp, zs, zd, elist, off + r*NN, hacc, NN);
  }
  k_bsum<<<1,128,0,stream>>>(b2, bsv);
  k_postln<1><<<ceil_div(NN*64,256),256,0,stream>>>(hacc, bsv, n2w, n2b, (short*)0, (short*)0, h2, NN);

  // --- attention pooling ---
  hipMemsetAsync(bmax, 0, (size_t)BB*sizeof(unsigned), stream);
  k_score<<<ceil_div(NN*64,256),256,0,stream>>>(h2, query, batch, zs, bmax, NN);
  k_segbounds<<<ceil_div(BB+1,256),256,0,stream>>>(batch, segst, NN, BB);
  k_pool<<<BB,128,0,stream>>>(h2, zs, segst, bmax, pool, BB);
  k_outgemm<<<BB,128,0,stream>>>(pool, projW, projb, out, BB);
}

// Round 4
// 1296.547 us; speedup vs baseline: 2.4362x; 1.2918x over previous
//
#include <hip/hip_runtime.h>
#include <math.h>

#define NN   100000
#define EE   800000
#define RR   6
#define BB   1000
#define HH   128
#define MM   (RR*NN)
#define NBPR ((NN + 255) >> 8)       // 391 buckets per relation (256 dst each)
#define NBK  (RR * NBPR)             // 2346
#define CH   4096                    // edges per binning chunk

static inline int ceil_div(int a, int b){ return (a+b-1)/b; }

typedef __attribute__((ext_vector_type(8))) short bf16x8;
typedef __attribute__((ext_vector_type(4))) short bf16x4;
typedef __attribute__((ext_vector_type(4))) float f32x4;

__device__ __forceinline__ unsigned fenc(float f){
  unsigned u = __float_as_uint(f);
  return (u & 0x80000000u) ? ~u : (u | 0x80000000u);
}
__device__ __forceinline__ float fdec(unsigned u){
  return __uint_as_float((u & 0x80000000u) ? (u & 0x7fffffffu) : ~u);
}
__device__ __forceinline__ unsigned short f2bf(float f){
  unsigned u = __float_as_uint(f);
  return (unsigned short)((u + 0x7fffu + ((u >> 16) & 1u)) >> 16);
}
__device__ __forceinline__ float bf2f(unsigned short h){
  return __uint_as_float(((unsigned)h) << 16);
}

// ================= bucketed CSR build (LDS-histogram binning) =================
__global__ void k_bcount(const int* __restrict__ edges, int* __restrict__ bcnt)
{
  __shared__ int hist[NBPR];
  int t = threadIdx.x;
  const int nch = (EE + CH - 1) / CH;
  int r = blockIdx.x / nch, c = blockIdx.x - r*nch;
  for (int i = t; i < NBPR; i += 256) hist[i] = 0;
  __syncthreads();
  const int* dptr = edges + (size_t)r*2*EE + EE;
  int e0 = c*CH, e1 = min(EE, e0 + CH);
  for (int i = e0 + t; i < e1; i += 256)
    atomicAdd(&hist[dptr[i] >> 8], 1);
  __syncthreads();
  for (int i = t; i < NBPR; i += 256) {
    int h = hist[i];
    if (h) atomicAdd(&bcnt[r*NBPR + i], h);
  }
}

__global__ void k_bscan(const int* __restrict__ bcnt, int* __restrict__ boff,
                        int* __restrict__ off)
{
  __shared__ int sh[256];
  int t = threadIdx.x;
  int carry = 0;
  for (int c = 0; c < NBK; c += 256) {
    int idx = c + t;
    int v = (idx < NBK) ? bcnt[idx] : 0;
    sh[t] = v;
    __syncthreads();
    for (int o = 1; o < 256; o <<= 1) {
      int add = (t >= o) ? sh[t-o] : 0;
      __syncthreads();
      sh[t] += add;
      __syncthreads();
    }
    int incl = sh[t];
    int tot  = sh[255];
    if (idx < NBK) boff[idx] = carry + incl - v;
    __syncthreads();
    carry += tot;
  }
  if (t == 0) { boff[NBK] = carry; off[MM] = carry; }
}

__global__ void k_binscatter(const int* __restrict__ edges, int* __restrict__ bcur,
                             unsigned* __restrict__ ebkt)
{
  __shared__ int hist[NBPR];
  __shared__ int base[NBPR];
  int t = threadIdx.x;
  const int nch = (EE + CH - 1) / CH;
  int r = blockIdx.x / nch, c = blockIdx.x - r*nch;
  for (int i = t; i < NBPR; i += 256) hist[i] = 0;
  __syncthreads();
  const int* sptr = edges + (size_t)r*2*EE;
  const int* dptr = sptr + EE;
  int e0 = c*CH, e1 = min(EE, e0 + CH);
  for (int i = e0 + t; i < e1; i += 256)
    atomicAdd(&hist[dptr[i] >> 8], 1);
  __syncthreads();
  for (int i = t; i < NBPR; i += 256) {
    int h = hist[i];
    base[i] = h ? atomicAdd(&bcur[r*NBPR + i], h) : 0;
    hist[i] = 0;
  }
  __syncthreads();
  for (int i = e0 + t; i < e1; i += 256) {
    int dst = dptr[i];
    int b = dst >> 8;
    int slot = base[b] + atomicAdd(&hist[b], 1);
    ebkt[slot] = ((unsigned)sptr[i] << 8) | (unsigned)(dst & 255);
  }
}

__global__ void k_bbuild(const unsigned* __restrict__ ebkt, const int* __restrict__ boff,
                         int* __restrict__ off, int* __restrict__ elist)
{
  __shared__ int cnt[256];
  __shared__ int sc[256];
  __shared__ int cur[256];
  int t = threadIdx.x;
  int bb = blockIdx.x;
  int e0 = boff[bb], e1 = boff[bb+1];
  cnt[t] = 0;
  __syncthreads();
  for (int i = e0 + t; i < e1; i += 256)
    atomicAdd(&cnt[ebkt[i] & 255u], 1);
  __syncthreads();
  sc[t] = cnt[t];
  __syncthreads();
  for (int o = 1; o < 256; o <<= 1) {
    int add = (t >= o) ? sc[t-o] : 0;
    __syncthreads();
    sc[t] += add;
    __syncthreads();
  }
  int excl = sc[t] - cnt[t];
  int r = bb / NBPR, b = bb - r*NBPR;
  int dst = b*256 + t;
  if (dst < NN) off[r*NN + dst] = e0 + excl;
  cur[t] = e0 + excl;
  __syncthreads();
  for (int i = e0 + t; i < e1; i += 256) {
    unsigned w = ebkt[i];
    int slot = atomicAdd(&cur[w & 255u], 1);
    elist[slot] = (int)(w >> 8);
  }
}

// ================= feature prep (bf16 hi/lo planes, K padded 21->32) =================
__global__ void k_featprep(const float* __restrict__ x_all, const float* __restrict__ pos_table,
                           short* __restrict__ x0h, short* __restrict__ x0l)
{
  int gid = blockIdx.x*256 + threadIdx.x;
  if (gid >= NN*32) return;
  int nidx = gid >> 5, c = gid & 31;
  float v = 0.f;
  if (c < 13) {
    int scl = (c < 5) ? c : c + 1;
    v = x_all[nidx*14 + scl];
  } else if (c < 21) {
    int pi = (int)x_all[nidx*14 + 5];
    pi = pi < 0 ? 0 : (pi > 23 ? 23 : pi);
    v = pos_table[pi*8 + (c - 13)];
  }
  unsigned short h = f2bf(v);
  unsigned short l = f2bf(v - bf2f(h));
  x0h[gid] = (short)h;
  x0l[gid] = (short)l;
}

// ================= weight prep =================
template<int KP>
__global__ void k_wprep(const float* __restrict__ W, int K,
                        short* __restrict__ Wh, short* __restrict__ Wl)
{
  int gid = blockIdx.x*256 + threadIdx.x;
  if (gid >= RR*128*KP) return;
  int r = gid / (128*KP);
  int rem = gid - r*(128*KP);
  int nn = rem / KP, k = rem - nn*KP;
  float v = (k < K) ? W[((size_t)r*K + k)*128 + nn] : 0.f;
  unsigned short h = f2bf(v);
  unsigned short l = f2bf(v - bf2f(h));
  Wh[gid] = (short)h;
  Wl[gid] = (short)l;
}

// ================= MFMA GEMM (split hi/lo bf16 ~ f32 accuracy), bf16 output =================
__device__ __forceinline__ bf16x8 ldfrag_(const short* p, int row, int kb, int KP_, int smask)
{
  int xr = row & smask;
  int s0 = (((kb)      >> 3) ^ xr) * 8 + (kb & 7);
  int s1 = (((kb + 16) >> 3) ^ xr) * 8 + (kb & 7);
  bf16x4 a = *(const bf16x4*)(p + (size_t)row*KP_ + s0);
  bf16x4 b = *(const bf16x4*)(p + (size_t)row*KP_ + s1);
  return __builtin_shufflevector(a, b, 0,1,2,3,4,5,6,7);
}

template<int KP>
__global__ __launch_bounds__(256, 2)
void k_gemm_mfma(const short* __restrict__ Ah, const short* __restrict__ Al,
                 const short* __restrict__ Wh, const short* __restrict__ Wl,
                 const float* __restrict__ a_s, const float* __restrict__ a_d,
                 unsigned short* __restrict__ xpb, float* __restrict__ zs, float* __restrict__ zd,
                 int n)
{
  constexpr int SLOTS = KP/8;
  constexpr int SMASK = (SLOTS >= 8) ? 7 : (SLOTS-1);
  __shared__ short lds[320*KP];
  constexpr int AH0 = 0, AL0 = 32*KP, WH0 = 64*KP, WL0 = 192*KP;
  int tid = threadIdx.x;
  int r0 = blockIdx.x * 32;

  for (int ch = tid; ch < 32*SLOTS; ch += 256) {
    int row = ch / SLOTS, slot = ch - row*SLOTS;
    int gr = r0 + row;
    int dsl = (slot ^ (row & SMASK)) * 8;
    bf16x8 vh, vl;
    if (gr < n) {
      vh = *(const bf16x8*)(Ah + (size_t)gr*KP + slot*8);
      vl = *(const bf16x8*)(Al + (size_t)gr*KP + slot*8);
    } else {
      #pragma unroll
      for (int q = 0; q < 8; ++q) { vh[q] = 0; vl[q] = 0; }
    }
    *(bf16x8*)(lds + AH0 + row*KP + dsl) = vh;
    *(bf16x8*)(lds + AL0 + row*KP + dsl) = vl;
  }
  for (int ch = tid; ch < 128*SLOTS; ch += 256) {
    int row = ch / SLOTS, slot = ch - row*SLOTS;
    int dsl = (slot ^ (row & SMASK)) * 8;
    *(bf16x8*)(lds + WH0 + row*KP + dsl) = *(const bf16x8*)(Wh + (size_t)row*KP + slot*8);
    *(bf16x8*)(lds + WL0 + row*KP + dsl) = *(const bf16x8*)(Wl + (size_t)row*KP + slot*8);
  }
  __syncthreads();

  int wid = tid >> 6, lane = tid & 63;
  int lr = lane & 15, lg = lane >> 4;
  int rt = wid >> 1;
  int c0 = (wid & 1) * 4;
  f32x4 acc[4] = {{0,0,0,0},{0,0,0,0},{0,0,0,0},{0,0,0,0}};
  int arow = rt*16 + lr;

  #pragma unroll
  for (int kc = 0; kc < KP/32; ++kc) {
    int kb = kc*32 + 4*lg;
    bf16x8 ah = ldfrag_(lds + AH0, arow, kb, KP, SMASK);
    bf16x8 al = ldfrag_(lds + AL0, arow, kb, KP, SMASK);
    #pragma unroll
    for (int t = 0; t < 4; ++t) {
      int wrow = (c0 + t)*16 + lr;
      bf16x8 wh = ldfrag_(lds + WH0, wrow, kb, KP, SMASK);
      bf16x8 wl = ldfrag_(lds + WL0, wrow, kb, KP, SMASK);
      acc[t] = __builtin_amdgcn_mfma_f32_16x16x32_bf16(ah, wh, acc[t], 0, 0, 0);
      acc[t] = __builtin_amdgcn_mfma_f32_16x16x32_bf16(ah, wl, acc[t], 0, 0, 0);
      acc[t] = __builtin_amdgcn_mfma_f32_16x16x32_bf16(al, wh, acc[t], 0, 0, 0);
    }
  }
  __syncthreads();

  float* Cs = (float*)lds;   // [32][136]
  #pragma unroll
  for (int t = 0; t < 4; ++t)
    #pragma unroll
    for (int v = 0; v < 4; ++v) {
      int row = rt*16 + lg*4 + v;
      int col = (c0 + t)*16 + lr;
      Cs[row*136 + col] = acc[t][v];
    }
  __syncthreads();

  {
    int r = tid >> 3, sg = tid & 7;
    float ps = 0.f, pd = 0.f;
    #pragma unroll
    for (int i = 0; i < 16; ++i) {
      int c = sg*16 + i;
      float x = Cs[r*136 + c];
      ps = fmaf(x, a_s[c], ps);
      pd = fmaf(x, a_d[c], pd);
    }
    ps += __shfl_xor(ps, 1); pd += __shfl_xor(pd, 1);
    ps += __shfl_xor(ps, 2); pd += __shfl_xor(pd, 2);
    ps += __shfl_xor(ps, 4); pd += __shfl_xor(pd, 4);
    int gr = r0 + r;
    if (sg == 0 && gr < n) { zs[gr] = ps; zd[gr] = pd; }
  }
  // bf16 output write: 8 cols per thread -> 16B stores
  for (int i = tid; i < 32*16; i += 256) {
    int row = i >> 4, q = i & 15;
    int gr = r0 + row;
    if (gr < n) {
      const float* cp = Cs + row*136 + q*8;
      uint4 o;
      o.x = ((unsigned)f2bf(cp[1]) << 16) | f2bf(cp[0]);
      o.y = ((unsigned)f2bf(cp[3]) << 16) | f2bf(cp[2]);
      o.z = ((unsigned)f2bf(cp[5]) << 16) | f2bf(cp[4]);
      o.w = ((unsigned)f2bf(cp[7]) << 16) | f2bf(cp[6]);
      *(uint4*)(xpb + (size_t)gr*128 + q*8) = o;
    }
  }
}

// ================= per-destination GAT aggregation (16-lane group per dst, bf16 gather) ==========
__global__ void k_agg(const unsigned short* __restrict__ xpb, const float* __restrict__ zs,
                      const float* __restrict__ zd, const int* __restrict__ elist,
                      const int* __restrict__ off, float* __restrict__ hacc, int n)
{
  int gid = blockIdx.x*256 + threadIdx.x;
  int g = gid >> 4;               // dst node, one per 16-lane group
  int l = threadIdx.x & 15;
  int gbase = threadIdx.x & 48;   // group base lane within wave
  if (g >= n) return;
  int o0 = off[g], o1 = off[g+1];
  int deg = o1 - o0;
  if (deg <= 0) return;
  float zdd = zd[g];

  float m = -3.4e38f;
  for (int i = l; i < deg; i += 16) {
    float z = zs[elist[o0+i]] + zdd;
    z = (z > 0.f) ? z : 0.2f*z;
    m = fmaxf(m, z);
  }
  m = fmaxf(m, __shfl_xor(m, 1));
  m = fmaxf(m, __shfl_xor(m, 2));
  m = fmaxf(m, __shfl_xor(m, 4));
  m = fmaxf(m, __shfl_xor(m, 8));

  float acc[8] = {0,0,0,0,0,0,0,0};
  float esum = 0.f;
  for (int base = 0; base < deg; base += 16) {
    int i = base + l;
    float ew = 0.f; int s = 0;
    if (i < deg) {
      s = elist[o0+i];
      float z = zs[s] + zdd;
      z = (z > 0.f) ? z : 0.2f*z;
      ew = __expf(z - m);
    }
    esum += ew;
    int cnt = min(16, deg - base);
    for (int t = 0; t < cnt; ++t) {
      float w = __shfl(ew, gbase + t);
      int ss = __shfl(s, gbase + t);
      const uint4 v = *(const uint4*)(xpb + (size_t)ss*128 + l*8);
      acc[0] = fmaf(w, __uint_as_float(v.x << 16),          acc[0]);
      acc[1] = fmaf(w, __uint_as_float(v.x & 0xffff0000u),  acc[1]);
      acc[2] = fmaf(w, __uint_as_float(v.y << 16),          acc[2]);
      acc[3] = fmaf(w, __uint_as_float(v.y & 0xffff0000u),  acc[3]);
      acc[4] = fmaf(w, __uint_as_float(v.z << 16),          acc[4]);
      acc[5] = fmaf(w, __uint_as_float(v.z & 0xffff0000u),  acc[5]);
      acc[6] = fmaf(w, __uint_as_float(v.w << 16),          acc[6]);
      acc[7] = fmaf(w, __uint_as_float(v.w & 0xffff0000u),  acc[7]);
    }
  }
  esum += __shfl_xor(esum, 1);
  esum += __shfl_xor(esum, 2);
  esum += __shfl_xor(esum, 4);
  esum += __shfl_xor(esum, 8);
  float inv = 1.f / esum;
  float* hp = hacc + (size_t)g*128 + l*8;
  float4 o0v = *(float4*)hp;
  float4 o1v = *(float4*)(hp + 4);
  o0v.x = fmaf(acc[0], inv, o0v.x);
  o0v.y = fmaf(acc[1], inv, o0v.y);
  o0v.z = fmaf(acc[2], inv, o0v.z);
  o0v.w = fmaf(acc[3], inv, o0v.w);
  o1v.x = fmaf(acc[4], inv, o1v.x);
  o1v.y = fmaf(acc[5], inv, o1v.y);
  o1v.z = fmaf(acc[6], inv, o1v.z);
  o1v.w = fmaf(acc[7], inv, o1v.w);
  *(float4*)hp = o0v;
  *(float4*)(hp + 4) = o1v;
}

// ================= bias-sum =================
__global__ void k_bsum(const float* __restrict__ b, float* __restrict__ bs)
{
  int t = threadIdx.x;
  float s = 0.f;
  #pragma unroll
  for (int r = 0; r < RR; ++r) s += b[r*HH + t];
  bs[t] = s;
}

// ================= gelu(exact) + LayerNorm, layer-1: bf16 hi/lo out =================
__global__ void k_postln1(const float* __restrict__ X, const float* __restrict__ bsum,
                          const float* __restrict__ nw, const float* __restrict__ nb,
                          short* __restrict__ Yh, short* __restrict__ Yl, int n)
{
  int wid = (int)((blockIdx.x*(size_t)blockDim.x + threadIdx.x) >> 6);
  int lane = threadIdx.x & 63;
  if (wid >= n) return;
  float2 x = *(const float2*)(X + (size_t)wid*128 + lane*2);
  x.x += bsum[lane*2];
  x.y += bsum[lane*2+1];
  float g0 = 0.5f*x.x*(1.f + erff(x.x*0.70710678118654752f));
  float g1 = 0.5f*x.y*(1.f + erff(x.y*0.70710678118654752f));
  float s = g0 + g1;
  #pragma unroll
  for (int o = 32; o > 0; o >>= 1) s += __shfl_xor(s, o);
  float mu = s * (1.f/128.f);
  float d0 = g0 - mu, d1 = g1 - mu;
  float v = d0*d0 + d1*d1;
  #pragma unroll
  for (int o = 32; o > 0; o >>= 1) v += __shfl_xor(v, o);
  v *= (1.f/128.f);
  float inv = 1.f / sqrtf(v + 1e-5f);
  float y0 = d0*inv*nw[lane*2]   + nb[lane*2];
  float y1 = d1*inv*nw[lane*2+1] + nb[lane*2+1];
  unsigned short h0 = f2bf(y0), h1 = f2bf(y1);
  unsigned short l0 = f2bf(y0 - bf2f(h0)), l1 = f2bf(y1 - bf2f(h1));
  short2 hh; hh.x = (short)h0; hh.y = (short)h1;
  short2 ll; ll.x = (short)l0; ll.y = (short)l1;
  *(short2*)(Yh + (size_t)wid*128 + lane*2) = hh;
  *(short2*)(Yl + (size_t)wid*128 + lane*2) = ll;
}

// ================= layer-2 postln: f32 out + fused attention score =================
__global__ void k_postln2(const float* __restrict__ X, const float* __restrict__ bsum,
                          const float* __restrict__ nw, const float* __restrict__ nb,
                          float* __restrict__ Yf, const float* __restrict__ q,
                          const int* __restrict__ batch, float* __restrict__ scores,
                          unsigned* __restrict__ bmax, int n)
{
  int wid = (int)((blockIdx.x*(size_t)blockDim.x + threadIdx.x) >> 6);
  int lane = threadIdx.x & 63;
  if (wid >= n) return;
  float2 x = *(const float2*)(X + (size_t)wid*128 + lane*2);
  x.x += bsum[lane*2];
  x.y += bsum[lane*2+1];
  float g0 = 0.5f*x.x*(1.f + erff(x.x*0.70710678118654752f));
  float g1 = 0.5f*x.y*(1.f + erff(x.y*0.70710678118654752f));
  float s = g0 + g1;
  #pragma unroll
  for (int o = 32; o > 0; o >>= 1) s += __shfl_xor(s, o);
  float mu = s * (1.f/128.f);
  float d0 = g0 - mu, d1 = g1 - mu;
  float v = d0*d0 + d1*d1;
  #pragma unroll
  for (int o = 32; o > 0; o >>= 1) v += __shfl_xor(v, o);
  v *= (1.f/128.f);
  float inv = 1.f / sqrtf(v + 1e-5f);
  float y0 = d0*inv*nw[lane*2]   + nb[lane*2];
  float y1 = d1*inv*nw[lane*2+1] + nb[lane*2+1];
  float2 y; y.x = y0; y.y = y1;
  *(float2*)(Yf + (size_t)wid*128 + lane*2) = y;
  // fused score
  float sc = y0*q[lane*2] + y1*q[lane*2+1];
  #pragma unroll
  for (int o = 32; o > 0; o >>= 1) sc += __shfl_xor(sc, o);
  if (lane == 0) {
    scores[wid] = sc;
    atomicMax(&bmax[batch[wid]], fenc(sc));
  }
}

// ================= pooling =================
__global__ void k_segbounds(const int* __restrict__ batch, int* __restrict__ segst,
                            int n, int numB)
{
  int b = blockIdx.x*256 + threadIdx.x;
  if (b > numB) return;
  int lo = 0, hi = n;
  while (lo < hi) { int mid = (lo+hi) >> 1; if (batch[mid] < b) lo = mid+1; else hi = mid; }
  segst[b] = lo;
}

__global__ void k_pool(const float* __restrict__ X, const float* __restrict__ scores,
                       const int* __restrict__ segst, const unsigned* __restrict__ bmax,
                       float* __restrict__ pool, int numB)
{
  int b = blockIdx.x;
  int t = threadIdx.x;
  int s0 = segst[b], s1 = segst[b+1];
  float m = fdec(bmax[b]);
  float acc = 0.f, esum = 0.f;
  for (int i = s0; i < s1; ++i) {
    float e = __expf(scores[i] - m);
    esum += e;
    acc = fmaf(e, X[(size_t)i*128 + t], acc);
  }
  float inv = (s1 > s0) ? 1.f/esum : 0.f;
  pool[(size_t)b*128 + t] = acc * inv;
}

__global__ void k_outgemm(const float* __restrict__ pool, const float* __restrict__ projW,
                          const float* __restrict__ projb, float* __restrict__ out, int numB)
{
  int b = blockIdx.x;
  int j = threadIdx.x;
  __shared__ float p[128];
  p[j] = pool[(size_t)b*128 + j];
  __syncthreads();
  float acc = projb[j];
  #pragma unroll 16
  for (int k = 0; k < 128; ++k) acc = fmaf(p[k], projW[(size_t)k*128 + j], acc);
  out[(size_t)b*128 + j] = acc;
}

// ================= launcher =================
extern "C" void kernel_launch(void* const* d_in, const int* in_sizes, int n_in,
                              void* d_out, int out_size, void* d_ws, size_t ws_size,
                              hipStream_t stream)
{
  const float* x_all = (const float*)d_in[0];
  const int*   edges = (const int*)d_in[1];
  const int*   batch = (const int*)d_in[2];
  const float* pos_table = (const float*)d_in[3];
  const float* W1  = (const float*)d_in[4];
  const float* as1 = (const float*)d_in[5];
  const float* ad1 = (const float*)d_in[6];
  const float* b1  = (const float*)d_in[7];
  const float* W2  = (const float*)d_in[8];
  const float* as2 = (const float*)d_in[9];
  const float* ad2 = (const float*)d_in[10];
  const float* b2  = (const float*)d_in[11];
  const float* n1w = (const float*)d_in[12];
  const float* n1b = (const float*)d_in[13];
  const float* n2w = (const float*)d_in[14];
  const float* n2b = (const float*)d_in[15];
  const float* query = (const float*)d_in[16];
  const float* projW = (const float*)d_in[17];
  const float* projb = (const float*)d_in[18];
  float* out = (float*)d_out;
  (void)in_sizes; (void)n_in; (void)out_size; (void)ws_size;

  char* p = (char*)d_ws;
  auto alloc = [&](size_t b){ void* r = (void*)p; p += (b + 255) & ~(size_t)255; return r; };
  int*   off   = (int*)alloc((size_t)(MM+1)*sizeof(int));
  int*   elist = (int*)alloc((size_t)RR*EE*sizeof(int));
  int*   bcnt  = (int*)alloc((size_t)NBK*sizeof(int));
  int*   boff  = (int*)alloc((size_t)(NBK+1)*sizeof(int));
  int*   bcur  = (int*)alloc((size_t)NBK*sizeof(int));
  short* wtH   = (short*)alloc((size_t)RR*128*128*sizeof(short));
  short* wtL   = (short*)alloc((size_t)RR*128*128*sizeof(short));
  float* zs    = (float*)alloc((size_t)NN*sizeof(float));
  float* zd    = (float*)alloc((size_t)NN*sizeof(float));
  float* bsv   = (float*)alloc(128*sizeof(float));
  int*   segst = (int*)alloc((size_t)(BB+1)*sizeof(int));
  unsigned* bmax = (unsigned*)alloc((size_t)BB*sizeof(unsigned));
  float* pool  = (float*)alloc((size_t)BB*HH*sizeof(float));
  float* bigA  = (float*)alloc((size_t)NN*128*sizeof(float));  // x0 planes, then h1 planes
  float* bigB  = (float*)alloc((size_t)NN*128*sizeof(float));  // xp bf16, then h2 f32
  float* bigC  = (float*)alloc((size_t)NN*128*sizeof(float));  // ebkt, then hacc

  short* x0h = (short*)bigA;                      // [N][32]
  short* x0l = (short*)bigA + (size_t)NN*32;
  short* h1h = (short*)bigA;                      // [N][128] (x0 dead by then)
  short* h1l = (short*)bigA + (size_t)NN*128;
  unsigned short* xpb = (unsigned short*)bigB;    // [N][128] bf16 gather table
  float* h2   = bigB;                             // f32 (xpb dead when written)
  unsigned* ebkt = (unsigned*)bigC;               // dead before hacc memset
  float* hacc = bigC;

  // --- CSR build (LDS-histogram binning, low-contention) ---
  const int nch = (EE + CH - 1) / CH;
  hipMemsetAsync(bcnt, 0, (size_t)NBK*sizeof(int), stream);
  k_bcount<<<RR*nch,256,0,stream>>>(edges, bcnt);
  k_bscan<<<1,256,0,stream>>>(bcnt, boff, off);
  hipMemcpyAsync(bcur, boff, (size_t)NBK*sizeof(int), hipMemcpyDeviceToDevice, stream);
  k_binscatter<<<RR*nch,256,0,stream>>>(edges, bcur, ebkt);
  k_bbuild<<<NBK,256,0,stream>>>(ebkt, boff, off, elist);

  // --- feature prep ---
  k_featprep<<<ceil_div(NN*32,256),256,0,stream>>>(x_all, pos_table, x0h, x0l);

  // --- layer 1 ---
  k_wprep<32><<<ceil_div(RR*128*32,256),256,0,stream>>>(W1, 21, wtH, wtL);
  hipMemsetAsync(hacc, 0, (size_t)NN*128*sizeof(float), stream);
  for (int r = 0; r < RR; ++r) {
    k_gemm_mfma<32><<<ceil_div(NN,32),256,0,stream>>>(
        x0h, x0l, wtH + (size_t)r*128*32, wtL + (size_t)r*128*32,
        as1 + r*HH, ad1 + r*HH, xpb, zs, zd, NN);
    k_agg<<<ceil_div(NN*16,256),256,0,stream>>>(xpb, zs, zd, elist, off + r*NN, hacc, NN);
  }
  k_bsum<<<1,128,0,stream>>>(b1, bsv);
  k_postln1<<<ceil_div(NN*64,256),256,0,stream>>>(hacc, bsv, n1w, n1b, h1h, h1l, NN);

  // --- layer 2 ---
  k_wprep<128><<<ceil_div(RR*128*128,256),256,0,stream>>>(W2, 128, wtH, wtL);
  hipMemsetAsync(hacc, 0, (size_t)NN*128*sizeof(float), stream);
  for (int r = 0; r < RR; ++r) {
    k_gemm_mfma<128><<<ceil_div(NN,32),256,0,stream>>>(
        h1h, h1l, wtH + (size_t)r*128*128, wtL + (size_t)r*128*128,
        as2 + r*HH, ad2 + r*HH, xpb, zs, zd, NN);
    k_agg<<<ceil_div(NN*16,256),256,0,stream>>>(xpb, zs, zd, elist, off + r*NN, hacc, NN);
  }
  k_bsum<<<1,128,0,stream>>>(b2, bsv);
  hipMemsetAsync(bmax, 0, (size_t)BB*sizeof(unsigned), stream);
  k_postln2<<<ceil_div(NN*64,256),256,0,stream>>>(hacc, bsv, n2w, n2b, h2,
                                                  query, batch, zs, bmax, NN);

  // --- attention pooling ---
  k_segbounds<<<ceil_div(BB+1,256),256,0,stream>>>(batch, segst, NN, BB);
  k_pool<<<BB,128,0,stream>>>(h2, zs, segst, bmax, pool, BB);
  k_outgemm<<<BB,128,0,stream>>>(pool, projW, projb, out, BB);
}

// Round 5
// 995.636 us; speedup vs baseline: 3.1725x; 1.3022x over previous
//
#include <hip/hip_runtime.h>
#include <math.h>

#define NN   100000
#define EE   800000
#define RR   6
#define BB   1000
#define HH   128
#define MM   (RR*NN)
#define NBPR ((NN + 255) >> 8)
#define NBK  (RR * NBPR)
#define CH   4096

static inline int ceil_div(int a, int b){ return (a+b-1)/b; }

typedef __attribute__((ext_vector_type(8))) short bf16x8;
typedef __attribute__((ext_vector_type(4))) short bf16x4;
typedef __attribute__((ext_vector_type(4))) float f32x4;

__device__ __forceinline__ unsigned fenc(float f){
  unsigned u = __float_as_uint(f);
  return (u & 0x80000000u) ? ~u : (u | 0x80000000u);
}
__device__ __forceinline__ float fdec(unsigned u){
  return __uint_as_float((u & 0x80000000u) ? (u & 0x7fffffffu) : ~u);
}
__device__ __forceinline__ unsigned short f2bf(float f){
  unsigned u = __float_as_uint(f);
  return (unsigned short)((u + 0x7fffu + ((u >> 16) & 1u)) >> 16);
}
__device__ __forceinline__ float bf2f(unsigned short h){
  return __uint_as_float(((unsigned)h) << 16);
}

// ================= bucketed CSR build (LDS-histogram binning) =================
__global__ void k_bcount(const int* __restrict__ edges, int* __restrict__ bcnt)
{
  __shared__ int hist[NBPR];
  int t = threadIdx.x;
  const int nch = (EE + CH - 1) / CH;
  int r = blockIdx.x / nch, c = blockIdx.x - r*nch;
  for (int i = t; i < NBPR; i += 256) hist[i] = 0;
  __syncthreads();
  const int* dptr = edges + (size_t)r*2*EE + EE;
  int e0 = c*CH, e1 = min(EE, e0 + CH);
  for (int i = e0 + t; i < e1; i += 256)
    atomicAdd(&hist[dptr[i] >> 8], 1);
  __syncthreads();
  for (int i = t; i < NBPR; i += 256) {
    int h = hist[i];
    if (h) atomicAdd(&bcnt[r*NBPR + i], h);
  }
}

__global__ void k_bscan(const int* __restrict__ bcnt, int* __restrict__ boff,
                        int* __restrict__ off)
{
  __shared__ int sh[256];
  int t = threadIdx.x;
  int carry = 0;
  for (int c = 0; c < NBK; c += 256) {
    int idx = c + t;
    int v = (idx < NBK) ? bcnt[idx] : 0;
    sh[t] = v;
    __syncthreads();
    for (int o = 1; o < 256; o <<= 1) {
      int add = (t >= o) ? sh[t-o] : 0;
      __syncthreads();
      sh[t] += add;
      __syncthreads();
    }
    int incl = sh[t];
    int tot  = sh[255];
    if (idx < NBK) boff[idx] = carry + incl - v;
    __syncthreads();
    carry += tot;
  }
  if (t == 0) { boff[NBK] = carry; off[MM] = carry; }
}

__global__ void k_binscatter(const int* __restrict__ edges, int* __restrict__ bcur,
                             unsigned* __restrict__ ebkt)
{
  __shared__ int hist[NBPR];
  __shared__ int base[NBPR];
  int t = threadIdx.x;
  const int nch = (EE + CH - 1) / CH;
  int r = blockIdx.x / nch, c = blockIdx.x - r*nch;
  for (int i = t; i < NBPR; i += 256) hist[i] = 0;
  __syncthreads();
  const int* sptr = edges + (size_t)r*2*EE;
  const int* dptr = sptr + EE;
  int e0 = c*CH, e1 = min(EE, e0 + CH);
  for (int i = e0 + t; i < e1; i += 256)
    atomicAdd(&hist[dptr[i] >> 8], 1);
  __syncthreads();
  for (int i = t; i < NBPR; i += 256) {
    int h = hist[i];
    base[i] = h ? atomicAdd(&bcur[r*NBPR + i], h) : 0;
    hist[i] = 0;
  }
  __syncthreads();
  for (int i = e0 + t; i < e1; i += 256) {
    int dst = dptr[i];
    int b = dst >> 8;
    int slot = base[b] + atomicAdd(&hist[b], 1);
    ebkt[slot] = ((unsigned)sptr[i] << 8) | (unsigned)(dst & 255);
  }
}

__global__ void k_bbuild(const unsigned* __restrict__ ebkt, const int* __restrict__ boff,
                         int* __restrict__ off, int* __restrict__ elist)
{
  __shared__ int cnt[256];
  __shared__ int sc[256];
  __shared__ int cur[256];
  int t = threadIdx.x;
  int bb = blockIdx.x;
  int e0 = boff[bb], e1 = boff[bb+1];
  cnt[t] = 0;
  __syncthreads();
  for (int i = e0 + t; i < e1; i += 256)
    atomicAdd(&cnt[ebkt[i] & 255u], 1);
  __syncthreads();
  sc[t] = cnt[t];
  __syncthreads();
  for (int o = 1; o < 256; o <<= 1) {
    int add = (t >= o) ? sc[t-o] : 0;
    __syncthreads();
    sc[t] += add;
    __syncthreads();
  }
  int excl = sc[t] - cnt[t];
  int r = bb / NBPR, b = bb - r*NBPR;
  int dst = b*256 + t;
  if (dst < NN) off[r*NN + dst] = e0 + excl;
  cur[t] = e0 + excl;
  __syncthreads();
  for (int i = e0 + t; i < e1; i += 256) {
    unsigned w = ebkt[i];
    int slot = atomicAdd(&cur[w & 255u], 1);
    elist[slot] = (int)(w >> 8);
  }
}

// ================= feature prep (bf16 hi/lo planes, K padded 21->32) =================
__global__ void k_featprep(const float* __restrict__ x_all, const float* __restrict__ pos_table,
                           short* __restrict__ x0h, short* __restrict__ x0l)
{
  int gid = blockIdx.x*256 + threadIdx.x;
  if (gid >= NN*32) return;
  int nidx = gid >> 5, c = gid & 31;
  float v = 0.f;
  if (c < 13) {
    int scl = (c < 5) ? c : c + 1;
    v = x_all[nidx*14 + scl];
  } else if (c < 21) {
    int pi = (int)x_all[nidx*14 + 5];
    pi = pi < 0 ? 0 : (pi > 23 ? 23 : pi);
    v = pos_table[pi*8 + (c - 13)];
  }
  unsigned short h = f2bf(v);
  unsigned short l = f2bf(v - bf2f(h));
  x0h[gid] = (short)h;
  x0l[gid] = (short)l;
}

// ================= weight prep =================
template<int KP>
__global__ void k_wprep(const float* __restrict__ W, int K,
                        short* __restrict__ Wh, short* __restrict__ Wl)
{
  int gid = blockIdx.x*256 + threadIdx.x;
  if (gid >= RR*128*KP) return;
  int r = gid / (128*KP);
  int rem = gid - r*(128*KP);
  int nn = rem / KP, k = rem - nn*KP;
  float v = (k < K) ? W[((size_t)r*K + k)*128 + nn] : 0.f;
  unsigned short h = f2bf(v);
  unsigned short l = f2bf(v - bf2f(h));
  Wh[gid] = (short)h;
  Wl[gid] = (short)l;
}

// ================= MFMA GEMM (split hi/lo bf16), 3 relations batched on blockIdx.y ======
__device__ __forceinline__ bf16x8 ldfrag_(const short* p, int row, int kb, int KP_, int smask)
{
  int xr = row & smask;
  int s0 = (((kb)      >> 3) ^ xr) * 8 + (kb & 7);
  int s1 = (((kb + 16) >> 3) ^ xr) * 8 + (kb & 7);
  bf16x4 a = *(const bf16x4*)(p + (size_t)row*KP_ + s0);
  bf16x4 b = *(const bf16x4*)(p + (size_t)row*KP_ + s1);
  return __builtin_shufflevector(a, b, 0,1,2,3,4,5,6,7);
}

template<int KP>
__global__ __launch_bounds__(256, 2)
void k_gemm_mfma(const short* __restrict__ Ah, const short* __restrict__ Al,
                 const short* __restrict__ WhAll, const short* __restrict__ WlAll,
                 const float* __restrict__ a_sAll, const float* __restrict__ a_dAll,
                 unsigned short* __restrict__ xpbAll, float* __restrict__ zsAll,
                 float* __restrict__ zdAll, int rbase, int n)
{
  constexpr int SLOTS = KP/8;
  constexpr int SMASK = (SLOTS >= 8) ? 7 : (SLOTS-1);
  __shared__ short lds[320*KP];
  constexpr int AH0 = 0, AL0 = 32*KP, WH0 = 64*KP, WL0 = 192*KP;
  int tid = threadIdx.x;
  int r0 = blockIdx.x * 32;
  int ry = blockIdx.y;
  const short* Wh = WhAll + (size_t)(rbase+ry)*128*KP;
  const short* Wl = WlAll + (size_t)(rbase+ry)*128*KP;
  const float* a_s = a_sAll + (size_t)(rbase+ry)*HH;
  const float* a_d = a_dAll + (size_t)(rbase+ry)*HH;
  unsigned short* xpb = xpbAll + (size_t)ry*n*128;
  float* zs = zsAll + (size_t)ry*n;
  float* zd = zdAll + (size_t)ry*n;

  for (int ch = tid; ch < 32*SLOTS; ch += 256) {
    int row = ch / SLOTS, slot = ch - row*SLOTS;
    int gr = r0 + row;
    int dsl = (slot ^ (row & SMASK)) * 8;
    bf16x8 vh, vl;
    if (gr < n) {
      vh = *(const bf16x8*)(Ah + (size_t)gr*KP + slot*8);
      vl = *(const bf16x8*)(Al + (size_t)gr*KP + slot*8);
    } else {
      #pragma unroll
      for (int q = 0; q < 8; ++q) { vh[q] = 0; vl[q] = 0; }
    }
    *(bf16x8*)(lds + AH0 + row*KP + dsl) = vh;
    *(bf16x8*)(lds + AL0 + row*KP + dsl) = vl;
  }
  for (int ch = tid; ch < 128*SLOTS; ch += 256) {
    int row = ch / SLOTS, slot = ch - row*SLOTS;
    int dsl = (slot ^ (row & SMASK)) * 8;
    *(bf16x8*)(lds + WH0 + row*KP + dsl) = *(const bf16x8*)(Wh + (size_t)row*KP + slot*8);
    *(bf16x8*)(lds + WL0 + row*KP + dsl) = *(const bf16x8*)(Wl + (size_t)row*KP + slot*8);
  }
  __syncthreads();

  int wid = tid >> 6, lane = tid & 63;
  int lr = lane & 15, lg = lane >> 4;
  int rt = wid >> 1;
  int c0 = (wid & 1) * 4;
  f32x4 acc[4] = {{0,0,0,0},{0,0,0,0},{0,0,0,0},{0,0,0,0}};
  int arow = rt*16 + lr;

  #pragma unroll
  for (int kc = 0; kc < KP/32; ++kc) {
    int kb = kc*32 + 4*lg;
    bf16x8 ah = ldfrag_(lds + AH0, arow, kb, KP, SMASK);
    bf16x8 al = ldfrag_(lds + AL0, arow, kb, KP, SMASK);
    #pragma unroll
    for (int t = 0; t < 4; ++t) {
      int wrow = (c0 + t)*16 + lr;
      bf16x8 wh = ldfrag_(lds + WH0, wrow, kb, KP, SMASK);
      bf16x8 wl = ldfrag_(lds + WL0, wrow, kb, KP, SMASK);
      acc[t] = __builtin_amdgcn_mfma_f32_16x16x32_bf16(ah, wh, acc[t], 0, 0, 0);
      acc[t] = __builtin_amdgcn_mfma_f32_16x16x32_bf16(ah, wl, acc[t], 0, 0, 0);
      acc[t] = __builtin_amdgcn_mfma_f32_16x16x32_bf16(al, wh, acc[t], 0, 0, 0);
    }
  }
  __syncthreads();

  float* Cs = (float*)lds;   // [32][136]
  #pragma unroll
  for (int t = 0; t < 4; ++t)
    #pragma unroll
    for (int v = 0; v < 4; ++v) {
      int row = rt*16 + lg*4 + v;
      int col = (c0 + t)*16 + lr;
      Cs[row*136 + col] = acc[t][v];
    }
  __syncthreads();

  {
    int r = tid >> 3, sg = tid & 7;
    float ps = 0.f, pd = 0.f;
    #pragma unroll
    for (int i = 0; i < 16; ++i) {
      int c = sg*16 + i;
      float x = Cs[r*136 + c];
      ps = fmaf(x, a_s[c], ps);
      pd = fmaf(x, a_d[c], pd);
    }
    ps += __shfl_xor(ps, 1); pd += __shfl_xor(pd, 1);
    ps += __shfl_xor(ps, 2); pd += __shfl_xor(pd, 2);
    ps += __shfl_xor(ps, 4); pd += __shfl_xor(pd, 4);
    int gr = r0 + r;
    if (sg == 0 && gr < n) { zs[gr] = ps; zd[gr] = pd; }
  }
  for (int i = tid; i < 32*16; i += 256) {
    int row = i >> 4, q = i & 15;
    int gr = r0 + row;
    if (gr < n) {
      const float* cp = Cs + row*136 + q*8;
      uint4 o;
      o.x = ((unsigned)f2bf(cp[1]) << 16) | f2bf(cp[0]);
      o.y = ((unsigned)f2bf(cp[3]) << 16) | f2bf(cp[2]);
      o.z = ((unsigned)f2bf(cp[5]) << 16) | f2bf(cp[4]);
      o.w = ((unsigned)f2bf(cp[7]) << 16) | f2bf(cp[6]);
      *(uint4*)(xpb + (size_t)gr*128 + q*8) = o;
    }
  }
}

// ================= mega-agg: 3 relations in registers, optional fused postln =============
// FIN=0: write hacc (f32). FIN=1: +hacc+bias, gelu+LN -> bf16 hi/lo planes.
// FIN=2: +hacc+bias, gelu+LN -> f32 + fused attention score.
template<int FIN>
__global__ void k_agg3(const unsigned short* __restrict__ xpb,  // [3][n][128]
                       const float* __restrict__ zs,            // [3][n]
                       const float* __restrict__ zd,
                       const int* __restrict__ elist,
                       const int* __restrict__ off,             // pre-offset by rbase*NN
                       float* __restrict__ hacc,
                       const float* __restrict__ bsum,
                       const float* __restrict__ nw, const float* __restrict__ nb,
                       short* __restrict__ Yh, short* __restrict__ Yl,
                       float* __restrict__ Yf,
                       const float* __restrict__ q,
                       const int* __restrict__ batch,
                       float* __restrict__ scores, unsigned* __restrict__ bmax,
                       int n)
{
  int gid = blockIdx.x*256 + threadIdx.x;
  int g = gid >> 4;
  int l = threadIdx.x & 15;
  int gbase = threadIdx.x & 48;
  if (g >= n) return;

  float acc[8] = {0,0,0,0,0,0,0,0};

  #pragma unroll
  for (int r = 0; r < 3; ++r) {
    int o0 = off[(size_t)r*NN + g], o1 = off[(size_t)r*NN + g + 1];
    int deg = o1 - o0;
    if (deg <= 0) continue;
    const float* zsr = zs + (size_t)r*n;
    float zdd = zd[(size_t)r*n + g];

    float m = -3.4e38f;
    for (int i = l; i < deg; i += 16) {
      float z = zsr[elist[o0+i]] + zdd;
      z = (z > 0.f) ? z : 0.2f*z;
      m = fmaxf(m, z);
    }
    m = fmaxf(m, __shfl_xor(m, 1));
    m = fmaxf(m, __shfl_xor(m, 2));
    m = fmaxf(m, __shfl_xor(m, 4));
    m = fmaxf(m, __shfl_xor(m, 8));

    float tmp[8] = {0,0,0,0,0,0,0,0};
    float esum = 0.f;
    const unsigned short* xr = xpb + (size_t)r*n*128;
    for (int base = 0; base < deg; base += 16) {
      int i = base + l;
      float ew = 0.f; int s = 0;
      if (i < deg) {
        s = elist[o0+i];
        float z = zsr[s] + zdd;
        z = (z > 0.f) ? z : 0.2f*z;
        ew = __expf(z - m);
      }
      esum += ew;
      int cnt = min(16, deg - base);
      for (int t = 0; t < cnt; ++t) {
        float w = __shfl(ew, gbase + t);
        int ss = __shfl(s, gbase + t);
        const uint4 v = *(const uint4*)(xr + (size_t)ss*128 + l*8);
        tmp[0] = fmaf(w, __uint_as_float(v.x << 16),          tmp[0]);
        tmp[1] = fmaf(w, __uint_as_float(v.x & 0xffff0000u),  tmp[1]);
        tmp[2] = fmaf(w, __uint_as_float(v.y << 16),          tmp[2]);
        tmp[3] = fmaf(w, __uint_as_float(v.y & 0xffff0000u),  tmp[3]);
        tmp[4] = fmaf(w, __uint_as_float(v.z << 16),          tmp[4]);
        tmp[5] = fmaf(w, __uint_as_float(v.z & 0xffff0000u),  tmp[5]);
        tmp[6] = fmaf(w, __uint_as_float(v.w << 16),          tmp[6]);
        tmp[7] = fmaf(w, __uint_as_float(v.w & 0xffff0000u),  tmp[7]);
      }
    }
    esum += __shfl_xor(esum, 1);
    esum += __shfl_xor(esum, 2);
    esum += __shfl_xor(esum, 4);
    esum += __shfl_xor(esum, 8);
    float inv = 1.f / esum;
    #pragma unroll
    for (int j = 0; j < 8; ++j) acc[j] = fmaf(tmp[j], inv, acc[j]);
  }

  if (FIN == 0) {
    float* hp = hacc + (size_t)g*128 + l*8;
    float4 o0; o0.x = acc[0]; o0.y = acc[1]; o0.z = acc[2]; o0.w = acc[3];
    float4 o1; o1.x = acc[4]; o1.y = acc[5]; o1.z = acc[6]; o1.w = acc[7];
    *(float4*)hp = o0;
    *(float4*)(hp + 4) = o1;
  } else {
    const float* hp = hacc + (size_t)g*128 + l*8;
    float4 p0 = *(const float4*)hp;
    float4 p1 = *(const float4*)(hp + 4);
    float4 b0 = *(const float4*)(bsum + l*8);
    float4 b1 = *(const float4*)(bsum + l*8 + 4);
    acc[0] += p0.x + b0.x; acc[1] += p0.y + b0.y;
    acc[2] += p0.z + b0.z; acc[3] += p0.w + b0.w;
    acc[4] += p1.x + b1.x; acc[5] += p1.y + b1.y;
    acc[6] += p1.z + b1.z; acc[7] += p1.w + b1.w;
    // exact gelu
    float s = 0.f;
    #pragma unroll
    for (int j = 0; j < 8; ++j) {
      acc[j] = 0.5f*acc[j]*(1.f + erff(acc[j]*0.70710678118654752f));
      s += acc[j];
    }
    s += __shfl_xor(s, 1); s += __shfl_xor(s, 2);
    s += __shfl_xor(s, 4); s += __shfl_xor(s, 8);
    float mu = s * (1.f/128.f);
    float v = 0.f;
    #pragma unroll
    for (int j = 0; j < 8; ++j) { acc[j] -= mu; v += acc[j]*acc[j]; }
    v += __shfl_xor(v, 1); v += __shfl_xor(v, 2);
    v += __shfl_xor(v, 4); v += __shfl_xor(v, 8);
    v *= (1.f/128.f);
    float inv = 1.f / sqrtf(v + 1e-5f);
    float4 w0 = *(const float4*)(nw + l*8);
    float4 w1 = *(const float4*)(nw + l*8 + 4);
    float4 nb0 = *(const float4*)(nb + l*8);
    float4 nb1 = *(const float4*)(nb + l*8 + 4);
    float y[8];
    y[0] = acc[0]*inv*w0.x + nb0.x; y[1] = acc[1]*inv*w0.y + nb0.y;
    y[2] = acc[2]*inv*w0.z + nb0.z; y[3] = acc[3]*inv*w0.w + nb0.w;
    y[4] = acc[4]*inv*w1.x + nb1.x; y[5] = acc[5]*inv*w1.y + nb1.y;
    y[6] = acc[6]*inv*w1.z + nb1.z; y[7] = acc[7]*inv*w1.w + nb1.w;
    if (FIN == 1) {
      uint4 oh, ol;
      unsigned short h0, h1;
      h0 = f2bf(y[0]); h1 = f2bf(y[1]);
      oh.x = ((unsigned)h1 << 16) | h0;
      ol.x = ((unsigned)f2bf(y[1]-bf2f(h1)) << 16) | f2bf(y[0]-bf2f(h0));
      h0 = f2bf(y[2]); h1 = f2bf(y[3]);
      oh.y = ((unsigned)h1 << 16) | h0;
      ol.y = ((unsigned)f2bf(y[3]-bf2f(h1)) << 16) | f2bf(y[2]-bf2f(h0));
      h0 = f2bf(y[4]); h1 = f2bf(y[5]);
      oh.z = ((unsigned)h1 << 16) | h0;
      ol.z = ((unsigned)f2bf(y[5]-bf2f(h1)) << 16) | f2bf(y[4]-bf2f(h0));
      h0 = f2bf(y[6]); h1 = f2bf(y[7]);
      oh.w = ((unsigned)h1 << 16) | h0;
      ol.w = ((unsigned)f2bf(y[7]-bf2f(h1)) << 16) | f2bf(y[6]-bf2f(h0));
      *(uint4*)((unsigned short*)Yh + (size_t)g*128 + l*8) = oh;
      *(uint4*)((unsigned short*)Yl + (size_t)g*128 + l*8) = ol;
    } else {
      float* yp = Yf + (size_t)g*128 + l*8;
      float4 o0; o0.x = y[0]; o0.y = y[1]; o0.z = y[2]; o0.w = y[3];
      float4 o1; o1.x = y[4]; o1.y = y[5]; o1.z = y[6]; o1.w = y[7];
      *(float4*)yp = o0;
      *(float4*)(yp + 4) = o1;
      float4 q0 = *(const float4*)(q + l*8);
      float4 q1 = *(const float4*)(q + l*8 + 4);
      float sc = y[0]*q0.x + y[1]*q0.y + y[2]*q0.z + y[3]*q0.w
               + y[4]*q1.x + y[5]*q1.y + y[6]*q1.z + y[7]*q1.w;
      sc += __shfl_xor(sc, 1); sc += __shfl_xor(sc, 2);
      sc += __shfl_xor(sc, 4); sc += __shfl_xor(sc, 8);
      if (l == 0) {
        scores[g] = sc;
        atomicMax(&bmax[batch[g]], fenc(sc));
      }
    }
  }
}

// ================= bias-sum =================
__global__ void k_bsum(const float* __restrict__ b, float* __restrict__ bs)
{
  int t = threadIdx.x;
  float s = 0.f;
  #pragma unroll
  for (int r = 0; r < RR; ++r) s += b[r*HH + t];
  bs[t] = s;
}

// ================= pooling =================
__global__ void k_segbounds(const int* __restrict__ batch, int* __restrict__ segst,
                            int n, int numB)
{
  int b = blockIdx.x*256 + threadIdx.x;
  if (b > numB) return;
  int lo = 0, hi = n;
  while (lo < hi) { int mid = (lo+hi) >> 1; if (batch[mid] < b) lo = mid+1; else hi = mid; }
  segst[b] = lo;
}

__global__ void k_pool(const float* __restrict__ X, const float* __restrict__ scores,
                       const int* __restrict__ segst, const unsigned* __restrict__ bmax,
                       float* __restrict__ pool, int numB)
{
  int b = blockIdx.x;
  int t = threadIdx.x;
  int s0 = segst[b], s1 = segst[b+1];
  float m = fdec(bmax[b]);
  float acc0 = 0.f, acc1 = 0.f, esum = 0.f;
  int i = s0;
  for (; i + 1 < s1; i += 2) {
    float e0 = __expf(scores[i] - m);
    float e1 = __expf(scores[i+1] - m);
    esum += e0 + e1;
    acc0 = fmaf(e0, X[(size_t)i*128 + t], acc0);
    acc1 = fmaf(e1, X[(size_t)(i+1)*128 + t], acc1);
  }
  if (i < s1) {
    float e0 = __expf(scores[i] - m);
    esum += e0;
    acc0 = fmaf(e0, X[(size_t)i*128 + t], acc0);
  }
  float inv = (s1 > s0) ? 1.f/esum : 0.f;
  pool[(size_t)b*128 + t] = (acc0 + acc1) * inv;
}

__global__ void k_outgemm(const float* __restrict__ pool, const float* __restrict__ projW,
                          const float* __restrict__ projb, float* __restrict__ out, int numB)
{
  int b = blockIdx.x;
  int j = threadIdx.x;
  __shared__ float p[128];
  p[j] = pool[(size_t)b*128 + j];
  __syncthreads();
  float acc = projb[j];
  #pragma unroll 16
  for (int k = 0; k < 128; ++k) acc = fmaf(p[k], projW[(size_t)k*128 + j], acc);
  out[(size_t)b*128 + j] = acc;
}

// ================= launcher =================
extern "C" void kernel_launch(void* const* d_in, const int* in_sizes, int n_in,
                              void* d_out, int out_size, void* d_ws, size_t ws_size,
                              hipStream_t stream)
{
  const float* x_all = (const float*)d_in[0];
  const int*   edges = (const int*)d_in[1];
  const int*   batch = (const int*)d_in[2];
  const float* pos_table = (const float*)d_in[3];
  const float* W1  = (const float*)d_in[4];
  const float* as1 = (const float*)d_in[5];
  const float* ad1 = (const float*)d_in[6];
  const float* b1  = (const float*)d_in[7];
  const float* W2  = (const float*)d_in[8];
  const float* as2 = (const float*)d_in[9];
  const float* ad2 = (const float*)d_in[10];
  const float* b2  = (const float*)d_in[11];
  const float* n1w = (const float*)d_in[12];
  const float* n1b = (const float*)d_in[13];
  const float* n2w = (const float*)d_in[14];
  const float* n2b = (const float*)d_in[15];
  const float* query = (const float*)d_in[16];
  const float* projW = (const float*)d_in[17];
  const float* projb = (const float*)d_in[18];
  float* out = (float*)d_out;
  (void)in_sizes; (void)n_in; (void)out_size; (void)ws_size;

  char* p = (char*)d_ws;
  auto alloc = [&](size_t b){ void* r = (void*)p; p += (b + 255) & ~(size_t)255; return r; };
  int*   off   = (int*)alloc((size_t)(MM+1)*sizeof(int));
  int*   elist = (int*)alloc((size_t)RR*EE*sizeof(int));
  int*   bcnt  = (int*)alloc((size_t)NBK*sizeof(int));
  int*   boff  = (int*)alloc((size_t)(NBK+1)*sizeof(int));
  int*   bcur  = (int*)alloc((size_t)NBK*sizeof(int));
  short* wtH   = (short*)alloc((size_t)RR*128*128*sizeof(short));
  short* wtL   = (short*)alloc((size_t)RR*128*128*sizeof(short));
  float* zs    = (float*)alloc((size_t)3*NN*sizeof(float));
  float* zd    = (float*)alloc((size_t)3*NN*sizeof(float));
  float* bsv   = (float*)alloc(128*sizeof(float));
  int*   segst = (int*)alloc((size_t)(BB+1)*sizeof(int));
  unsigned* bmax = (unsigned*)alloc((size_t)BB*sizeof(unsigned));
  float* pool  = (float*)alloc((size_t)BB*HH*sizeof(float));
  float* scrs  = (float*)alloc((size_t)NN*sizeof(float));
  unsigned short* xpb = (unsigned short*)alloc((size_t)3*NN*128*sizeof(unsigned short)); // 76.8MB
  float* hacc  = (float*)alloc((size_t)NN*128*sizeof(float));   // 51.2MB (ebkt aliases front)
  float* bigA  = (float*)alloc((size_t)NN*128*sizeof(float));   // x0 planes / h1 planes / h2

  short* x0h = (short*)bigA;                      // [N][32]
  short* x0l = (short*)bigA + (size_t)NN*32;
  short* h1h = (short*)bigA;                      // [N][128] (x0 dead)
  short* h1l = (short*)bigA + (size_t)NN*128;
  float* h2  = bigA;                              // f32 (h1 dead after L2 gemms)
  unsigned* ebkt = (unsigned*)hacc;               // dead before hacc first write

  // --- CSR build ---
  const int nch = (EE + CH - 1) / CH;
  hipMemsetAsync(bcnt, 0, (size_t)NBK*sizeof(int), stream);
  k_bcount<<<RR*nch,256,0,stream>>>(edges, bcnt);
  k_bscan<<<1,256,0,stream>>>(bcnt, boff, off);
  hipMemcpyAsync(bcur, boff, (size_t)NBK*sizeof(int), hipMemcpyDeviceToDevice, stream);
  k_binscatter<<<RR*nch,256,0,stream>>>(edges, bcur, ebkt);
  k_bbuild<<<NBK,256,0,stream>>>(ebkt, boff, off, elist);

  // --- feature prep + misc ---
  k_featprep<<<ceil_div(NN*32,256),256,0,stream>>>(x_all, pos_table, x0h, x0l);
  k_segbounds<<<ceil_div(BB+1,256),256,0,stream>>>(batch, segst, NN, BB);
  hipMemsetAsync(bmax, 0, (size_t)BB*sizeof(unsigned), stream);

  dim3 g3(ceil_div(NN,32), 3);
  int aggGrid = ceil_div(NN*16, 256);

  // --- layer 1 ---
  k_wprep<32><<<ceil_div(RR*128*32,256),256,0,stream>>>(W1, 21, wtH, wtL);
  k_bsum<<<1,128,0,stream>>>(b1, bsv);
  k_gemm_mfma<32><<<g3,256,0,stream>>>(x0h, x0l, wtH, wtL, as1, ad1, xpb, zs, zd, 0, NN);
  k_agg3<0><<<aggGrid,256,0,stream>>>(xpb, zs, zd, elist, off, hacc,
      bsv, n1w, n1b, (short*)0, (short*)0, (float*)0, query, batch, scrs, bmax, NN);
  k_gemm_mfma<32><<<g3,256,0,stream>>>(x0h, x0l, wtH, wtL, as1, ad1, xpb, zs, zd, 3, NN);
  k_agg3<1><<<aggGrid,256,0,stream>>>(xpb, zs, zd, elist, off + (size_t)3*NN, hacc,
      bsv, n1w, n1b, h1h, h1l, (float*)0, query, batch, scrs, bmax, NN);

  // --- layer 2 ---
  k_wprep<128><<<ceil_div(RR*128*128,256),256,0,stream>>>(W2, 128, wtH, wtL);
  k_bsum<<<1,128,0,stream>>>(b2, bsv);
  k_gemm_mfma<128><<<g3,256,0,stream>>>(h1h, h1l, wtH, wtL, as2, ad2, xpb, zs, zd, 0, NN);
  k_agg3<0><<<aggGrid,256,0,stream>>>(xpb, zs, zd, elist, off, hacc,
      bsv, n2w, n2b, (short*)0, (short*)0, (float*)0, query, batch, scrs, bmax, NN);
  k_gemm_mfma<128><<<g3,256,0,stream>>>(h1h, h1l, wtH, wtL, as2, ad2, xpb, zs, zd, 3, NN);
  k_agg3<2><<<aggGrid,256,0,stream>>>(xpb, zs, zd, elist, off + (size_t)3*NN, hacc,
      bsv, n2w, n2b, (short*)0, (short*)0, h2, query, batch, scrs, bmax, NN);

  // --- attention pooling ---
  k_pool<<<BB,128,0,stream>>>(h2, scrs, segst, bmax, pool, BB);
  k_outgemm<<<BB,128,0,stream>>>(pool, projW, projb, out, BB);
}